// Round 2
// baseline (575.832 us; speedup 1.0000x reference)
//
#include <hip/hip_runtime.h>
#include <cstdint>
#include <cstddef>

typedef __bf16 bf16;
typedef __bf16 bf16x8 __attribute__((ext_vector_type(8)));
typedef float f32x4 __attribute__((ext_vector_type(4)));

#define DEV static __device__ __forceinline__

constexpr int BATCH = 8;
constexpr int SEQ = 4096;
constexpr int DIM = 512;
constexpr int HEADS = 8;
constexpr int DH = 64;
constexpr int WIN = 128;
constexpr int NW = SEQ / WIN;        // 32
constexpr int TOK = BATCH * SEQ;     // 32768
constexpr float EPS = 1e-5f;

// canonical bf16 weights in workspace (element offsets)
constexpr size_t R_EL   = (size_t)TOK * DIM;            // 16,777,216
constexpr size_t C_QKV  = 0;                             // 786432
constexpr size_t C_WOUT = 786432;                        // 262144
constexpr size_t C_WF1  = 1048576;                       // 1048576
constexpr size_t C_WF2  = 2097152;                       // 1048576
constexpr size_t C_SM   = 3145728;                       // 2688 smalls
// smalls: qsc 0, ksc 64, bout 128, l1g 640, l1b 1152, lfg 1664, lfb 2176
constexpr size_t P_EL   = 3148416;                       // slot base (%8==0)

DEV void gload_lds16(const void* g, void* l) {
  __builtin_amdgcn_global_load_lds((__attribute__((address_space(1))) void*)g,
                                   (__attribute__((address_space(3))) void*)l,
                                   16, 0, 0);
}

DEV f32x4 mfma16(bf16x8 a, bf16x8 b, f32x4 c) {
  return __builtin_amdgcn_mfma_f32_16x16x32_bf16(a, b, c, 0, 0, 0);
}

// Branchless exact-GELU via Abramowitz-Stegun 7.1.26 erf approximation.
DEV float fast_gelu(float v) {
  const float z = fabsf(v) * 0.7071067811865476f;
  const float t = __builtin_amdgcn_rcpf(1.0f + 0.3275911f * z);
  const float p = t * (0.254829592f +
                  t * (-0.284496736f +
                  t * (1.421413741f +
                  t * (-1.453152027f +
                  t * 1.061405429f))));
  const float e = __expf(-z * z);
  const float erfa = 1.0f - p * e;               // erf(|v|/sqrt2)
  const float cdf = 0.5f + copysignf(0.5f * erfa, v);
  return v * cdf;
}

// ---------------- ingest: dtype-probe + convert weight inputs to bf16 ----------
struct SrcPtrs { const void* p[12]; };

DEV void copy8(const void* src, long si, bf16* dst, bool f32) {
  if (f32) {
    const float4* s = (const float4*)((const float*)src + si);
    float4 a = s[0], b = s[1];
    bf16x8 o;
    o[0] = (bf16)a.x; o[1] = (bf16)a.y; o[2] = (bf16)a.z; o[3] = (bf16)a.w;
    o[4] = (bf16)b.x; o[5] = (bf16)b.y; o[6] = (bf16)b.z; o[7] = (bf16)b.w;
    *(bf16x8*)dst = o;
  } else {
    *(bf16x8*)dst = *(const bf16x8*)((const bf16*)src + si);
  }
}

__global__ __launch_bounds__(256) void ingest_kernel(SrcPtrs sp, bf16* cano) {
  const bool f32 = (((const unsigned short*)sp.p[2])[0] == 0);
  const long e = (long)threadIdx.x * 8;
  int b = blockIdx.x;
  if (b < 384)  { long o = (long)b * 2048 + e; copy8(sp.p[1], o, cano + C_QKV + o, f32); return; }
  b -= 384;
  if (b < 128)  { long o = (long)b * 2048 + e; copy8(sp.p[4], o, cano + C_WOUT + o, f32); return; }
  b -= 128;
  if (b < 512)  { long o = (long)b * 2048 + e; copy8(sp.p[10], o, cano + C_WF1 + o, f32); return; }
  b -= 512;
  if (b < 512)  { long o = (long)b * 2048 + e; copy8(sp.p[11], o, cano + C_WF2 + o, f32); return; }
  b -= 512;
  const long o = (long)b * 2048 + e;
  if (o >= 2688) return;
  const void* src; long si;
  if      (o < 64)   { src = sp.p[2]; si = o; }
  else if (o < 128)  { src = sp.p[3]; si = o - 64; }
  else if (o < 640)  { src = sp.p[5]; si = o - 128; }
  else if (o < 1152) { src = sp.p[6]; si = o - 640; }
  else if (o < 1664) { src = sp.p[7]; si = o - 1152; }
  else if (o < 2176) { src = sp.p[8]; si = o - 1664; }
  else               { src = sp.p[9]; si = o - 2176; }
  copy8(src, si, cano + C_SM + o, f32);
}

// ---------------- LayerNorm: one wave per 512-dim token ----------------
__global__ __launch_bounds__(256) void ln_kernel(const void* __restrict__ in,
                                                 const bf16* __restrict__ gg,
                                                 const bf16* __restrict__ bb,
                                                 bf16* __restrict__ out,
                                                 const unsigned short* __restrict__ probe,
                                                 int raw) {
  const int wave = threadIdx.x >> 6, lane = threadIdx.x & 63;
  const int row = blockIdx.x * 4 + wave;
  const size_t base = (size_t)row * DIM + lane * 8;
  float f[8];
  if (raw && probe[0] == 0) {
    const float4* p = (const float4*)((const float*)in + base);
    float4 a = p[0], bq = p[1];
    f[0] = a.x; f[1] = a.y; f[2] = a.z; f[3] = a.w;
    f[4] = bq.x; f[5] = bq.y; f[6] = bq.z; f[7] = bq.w;
  } else {
    bf16x8 v = *(const bf16x8*)((const bf16*)in + base);
#pragma unroll
    for (int i = 0; i < 8; ++i) f[i] = (float)v[i];
  }
  float s = 0.f, sq = 0.f;
#pragma unroll
  for (int i = 0; i < 8; ++i) { s += f[i]; sq += f[i] * f[i]; }
#pragma unroll
  for (int m = 32; m; m >>= 1) { s += __shfl_xor(s, m); sq += __shfl_xor(sq, m); }
  const float mean = s * (1.0f / DIM);
  const float var = fmaxf(sq * (1.0f / DIM) - mean * mean, 0.0f);
  const float rs = rsqrtf(var + EPS);
  bf16x8 gv = *(const bf16x8*)(gg + lane * 8);
  bf16x8 bv = *(const bf16x8*)(bb + lane * 8);
  bf16x8 o;
#pragma unroll
  for (int i = 0; i < 8; ++i) o[i] = (bf16)((f[i] - mean) * rs * (float)gv[i] + (float)bv[i]);
  *(bf16x8*)((bf16*)out + base) = o;
}

// ---------------- 256x256 8-phase GEMM: C = A(MxK) @ Bw(N x K)^T ----------------
// HK-derived schedule (T2 swizzle + T3/T4 counted vmcnt + T5 setprio), plain HIP.
// 8 waves (2M x 4N), BK=64, 128 KiB LDS (2 dbuf x (A 256x64 + B 256x64) bf16).
// Per iteration: 2 K-tiles, 8 phases; each phase = {ds_read subtile | stage 1
// half-tile | barrier | lgkmcnt(0) | 16 MFMA} ; vmcnt(4) only at phases 4/8.
// Stage ledger (tile t2 in buf0 phases 0-3, t2+1 in buf1 phases 4-7):
//   p0:A0(t2+1)->buf1 p1:A1(t2+1) p2:B0(t2+2)->buf0 p3:B1(t2+2)
//   p4:A0(t2+2)->buf0 p5:A1(t2+2) p6:B0(t2+3)->buf1 p7:B1(t2+3)
// Every region is overwritten strictly after its last read (A reads end p2/p6,
// B reads end p1/p5); vmcnt(4) before the p3/p7 barrier covers the 4 oldest
// in-flight half-tiles = exactly the tile consumed next.
// LDS swizzle: elem (r,c) stored at r*64 + (c ^ ((r&7)<<3)); staged via
// inverse-swizzled GLOBAL source with linear LDS dest (rule #21).

#define SYNC_PRE \
  __builtin_amdgcn_sched_barrier(0); \
  __builtin_amdgcn_s_barrier(); \
  asm volatile("s_waitcnt lgkmcnt(0)" ::: "memory"); \
  __builtin_amdgcn_sched_barrier(0); \
  __builtin_amdgcn_s_setprio(1);

#define SYNC_POST \
  __builtin_amdgcn_s_setprio(0); \
  __builtin_amdgcn_sched_barrier(0); \
  __builtin_amdgcn_s_barrier();

#define SYNC_POST_VM \
  __builtin_amdgcn_s_setprio(0); \
  __builtin_amdgcn_sched_barrier(0); \
  asm volatile("s_waitcnt vmcnt(4)" ::: "memory"); \
  __builtin_amdgcn_s_barrier();

#define RD_A4(D, MB) \
  _Pragma("unroll") for (int mf = 0; mf < 4; ++mf) { \
    a[mf][0] = *(const bf16x8*)&smem[(D) * 32768 + arow0 + ((MB) + mf) * 1024 + kq0]; \
    a[mf][1] = *(const bf16x8*)&smem[(D) * 32768 + arow0 + ((MB) + mf) * 1024 + kq1]; \
  }

#define RD_B2(D, NB, BR) \
  _Pragma("unroll") for (int nf = 0; nf < 2; ++nf) { \
    BR[nf][0] = *(const bf16x8*)&smem[(D) * 32768 + brow0 + ((NB) + nf) * 1024 + kq0]; \
    BR[nf][1] = *(const bf16x8*)&smem[(D) * 32768 + brow0 + ((NB) + nf) * 1024 + kq1]; \
  }

#define MFMA_Q(MB, NB, BR) \
  _Pragma("unroll") for (int mf = 0; mf < 4; ++mf) \
  _Pragma("unroll") for (int nf = 0; nf < 2; ++nf) { \
    acc[(MB) + mf][(NB) + nf] = mfma16(a[mf][0], BR[nf][0], acc[(MB) + mf][(NB) + nf]); \
    acc[(MB) + mf][(NB) + nf] = mfma16(a[mf][1], BR[nf][1], acc[(MB) + mf][(NB) + nf]); \
  }

template <int MODE>
__global__ __launch_bounds__(512, 2) void gemm8(const bf16* __restrict__ A,
                                                const bf16* __restrict__ Bw,
                                                bf16* __restrict__ O0, bf16* __restrict__ O1,
                                                bf16* __restrict__ O2,
                                                float* __restrict__ Of,
                                                const void* __restrict__ Xraw,
                                                const bf16* __restrict__ Xb,
                                                const bf16* __restrict__ bias,
                                                const unsigned short* __restrict__ probe,
                                                int K, int bstride, int ostride, int gx) {
  extern __shared__ __align__(16) bf16 smem[];        // 131072 B
  const int tid = threadIdx.x;
  const int wid = tid >> 6, lane = tid & 63;
  const int l15 = lane & 15, quad = lane >> 4;
  const int wm = wid >> 2, wn = wid & 3;
  const int id = blockIdx.x;
  const int per = gx * 8;
  const int tM = ((id / per) * 8 + (id & 7)) * 256;   // XCD-aware swizzle
  const int tN = ((id % per) >> 3) * 256;

  // swizzled read addressing
  const int sw = (l15 & 7) << 3;
  const int kq0 = (quad * 8) ^ sw;
  const int kq1 = (32 + quad * 8) ^ sw;
  const int arow0 = (wm * 128 + l15) * 64;
  const int brow0 = (wn * 64 + l15) * 64 + 16384;

  // staging addressing (linear LDS dest, inverse-swizzled global col)
  const int srow = wid * 16 + (lane >> 3);            // 0..127 (j adds 8)
  const int scol = ((lane & 7) ^ (lane >> 3)) << 3;

  auto stageA = [&](int d, int h, int T) {
    const size_t g0 = (size_t)(tM + h * 128 + srow) * K + T * 64 + scol;
    bf16* dst = smem + d * 32768 + h * 8192 + wid * 1024 + lane * 8;
#pragma unroll
    for (int j = 0; j < 2; ++j)
      gload_lds16(A + g0 + (size_t)j * 8 * K, dst + j * 512);
  };
  auto stageB = [&](int d, int h, int T) {
    const size_t g0 = (size_t)(tN + h * 128 + srow) * bstride + T * 64 + scol;
    bf16* dst = smem + d * 32768 + 16384 + h * 8192 + wid * 1024 + lane * 8;
#pragma unroll
    for (int j = 0; j < 2; ++j)
      gload_lds16(Bw + g0 + (size_t)j * 8 * bstride, dst + j * 512);
  };

  f32x4 acc[8][4];
  const f32x4 z = {0.f, 0.f, 0.f, 0.f};
#pragma unroll
  for (int i = 0; i < 8; ++i)
#pragma unroll
    for (int j = 0; j < 4; ++j) acc[i][j] = z;

  bf16x8 a[4][2], b01[2][2], b23[2][2];

  // prologue: tile0 all 4 halves -> buf0, tile1 B halves -> buf1
  stageA(0, 0, 0); stageA(0, 1, 0); stageB(0, 0, 0); stageB(0, 1, 0);
  stageB(1, 0, 1); stageB(1, 1, 1);
  asm volatile("s_waitcnt vmcnt(4)" ::: "memory");    // tile0 landed
  __builtin_amdgcn_s_barrier();

  const int nt = K >> 6;
  for (int t2 = 0; t2 < nt; t2 += 2) {
    const int tn2 = (t2 + 2 < nt) ? t2 + 2 : nt - 1;  // clamped (garbage lands
    const int tn3 = (t2 + 3 < nt) ? t2 + 3 : nt - 1;  //  post-last-read only)
    // ---- tile t2 from buf0 ----
    RD_A4(0, 0); RD_B2(0, 0, b01);
    stageA(1, 0, t2 + 1);
    SYNC_PRE; MFMA_Q(0, 0, b01); SYNC_POST;
    RD_B2(0, 2, b23);
    stageA(1, 1, t2 + 1);
    SYNC_PRE; MFMA_Q(0, 2, b23); SYNC_POST;
    RD_A4(0, 4);
    stageB(0, 0, tn2);
    SYNC_PRE; MFMA_Q(4, 2, b23); SYNC_POST;
    stageB(0, 1, tn2);
    SYNC_PRE; MFMA_Q(4, 0, b01); SYNC_POST_VM;
    // ---- tile t2+1 from buf1 ----
    RD_A4(1, 0); RD_B2(1, 0, b01);
    stageA(0, 0, tn2);
    SYNC_PRE; MFMA_Q(0, 0, b01); SYNC_POST;
    RD_B2(1, 2, b23);
    stageA(0, 1, tn2);
    SYNC_PRE; MFMA_Q(0, 2, b23); SYNC_POST;
    RD_A4(1, 4);
    stageB(1, 0, tn3);
    SYNC_PRE; MFMA_Q(4, 2, b23); SYNC_POST;
    stageB(1, 1, tn3);
    SYNC_PRE; MFMA_Q(4, 0, b01); SYNC_POST_VM;
  }

  if constexpr (MODE == 0) {
    // wave's 64-col span is exactly one (q/k/v, head) plane; fused rope for q/k
    __syncthreads();                              // drains stray stages too
    bf16* ob = smem + wid * 1152;                 // per-wave 16 x 72 tile
    const int colbase = tN + wn * 64;
    const int which = colbase >> 9;
    const int head = (colbase >> 6) & 7;
    bf16* dst = which == 0 ? O0 : (which == 1 ? O1 : O2);
    const int ch = lane & 7;
    float scv[8], invf[8];
    if (which < 2) {
      const bf16* sc = which ? bias : Xb;         // ksc : qsc
      bf16x8 s8 = *(const bf16x8*)(sc + ch * 8);
#pragma unroll
      for (int u = 0; u < 8; ++u) {
        scv[u] = (float)s8[u] * (which == 0 ? 8.0f : 1.0f);   // fold QK_SCALE into q
        invf[u] = exp2f(-(float)((ch & 3) * 8 + u) * (13.287712379549449f / 32.0f));
      }
    }
#pragma unroll
    for (int i = 0; i < 8; ++i) {
#pragma unroll
      for (int j = 0; j < 4; ++j)
#pragma unroll
        for (int r = 0; r < 4; ++r)
          ob[(quad * 4 + r) * 72 + j * 16 + l15] = (bf16)acc[i][j][r];
#pragma unroll
      for (int t = 0; t < 2; ++t) {
        const int rr = t * 8 + (lane >> 3);
        const int rowg = tM + wm * 128 + i * 16 + rr;
        bf16x8 ov = *(const bf16x8*)&ob[rr * 72 + ch * 8];
        float f[8];
#pragma unroll
        for (int u = 0; u < 8; ++u) f[u] = (float)ov[u];
        if (which < 2) {
          float ss = 0.f;
#pragma unroll
          for (int u = 0; u < 8; ++u) ss += f[u] * f[u];
          ss += __shfl_xor(ss, 1); ss += __shfl_xor(ss, 2); ss += __shfl_xor(ss, 4);
          const float rs = 1.0f / fmaxf(sqrtf(ss), 1e-12f);
#pragma unroll
          for (int u = 0; u < 8; ++u) f[u] *= rs * scv[u];
          float pf[8];
#pragma unroll
          for (int u = 0; u < 8; ++u) pf[u] = __shfl_xor(f[u], 4);
          const float pos = (float)(rowg & (SEQ - 1));
#pragma unroll
          for (int u = 0; u < 8; ++u) {
            float sn, cs;
            __sincosf(pos * invf[u], &sn, &cs);
            const float rot = (ch < 4) ? -pf[u] : pf[u];
            f[u] = f[u] * cs + rot * sn;
          }
        }
        bf16x8 o8;
#pragma unroll
        for (int u = 0; u < 8; ++u) o8[u] = (bf16)f[u];
        const int bb = rowg >> 12, n = rowg & (SEQ - 1);
        *(bf16x8*)(dst + ((size_t)(bb * HEADS + head) * SEQ + n) * DH + ch * 8) = o8;
      }
    }
    return;
  }

  if constexpr (MODE == 1 || MODE == 2) {
    // coalesced epilogue via per-wave LDS restage
    __syncthreads();
    bf16* ob = smem + wid * 1152;                 // 16 x 72
    const int ch = lane & 7;
    bf16x8 bias8;
    bool xf32 = false;
    if constexpr (MODE == 1) {
      bias8 = *(const bf16x8*)(bias + tN + wn * 64 + ch * 8);
      xf32 = (probe[0] == 0);
    }
#pragma unroll
    for (int i = 0; i < 8; ++i) {
#pragma unroll
      for (int j = 0; j < 4; ++j)
#pragma unroll
        for (int r = 0; r < 4; ++r)
          ob[(quad * 4 + r) * 72 + j * 16 + l15] = (bf16)acc[i][j][r];
#pragma unroll
      for (int t = 0; t < 2; ++t) {
        const int rr = t * 8 + (lane >> 3);
        const int rowg = tM + wm * 128 + i * 16 + rr;
        bf16x8 ov = *(const bf16x8*)&ob[rr * 72 + ch * 8];
        bf16x8 o8;
        if constexpr (MODE == 1) {
          const size_t idx = (size_t)rowg * DIM + tN + wn * 64 + ch * 8;
          float xr[8];
          if (xf32) {
            const float4* xp = (const float4*)((const float*)Xraw + idx);
            float4 aa = xp[0], bq = xp[1];
            xr[0] = aa.x; xr[1] = aa.y; xr[2] = aa.z; xr[3] = aa.w;
            xr[4] = bq.x; xr[5] = bq.y; xr[6] = bq.z; xr[7] = bq.w;
          } else {
            bf16x8 xv = *(const bf16x8*)((const bf16*)Xraw + idx);
#pragma unroll
            for (int u = 0; u < 8; ++u) xr[u] = (float)xv[u];
          }
#pragma unroll
          for (int u = 0; u < 8; ++u) o8[u] = (bf16)((float)ov[u] + xr[u] + (float)bias8[u]);
          *(bf16x8*)(O0 + idx) = o8;
        } else {
#pragma unroll
          for (int u = 0; u < 8; ++u) o8[u] = (bf16)fast_gelu((float)ov[u]);
          *(bf16x8*)(O0 + (size_t)rowg * ostride + tN + wn * 64 + ch * 8) = o8;
        }
      }
    }
    return;
  }

  if constexpr (MODE == 3 || MODE == 4) {
    // fp32 LDS restage -> float4 stores
    __syncthreads();
    float* obf = (float*)smem + wid * 1088;       // 16 x 68 floats
    const int ch = lane & 7;
#pragma unroll
    for (int i = 0; i < 8; ++i) {
#pragma unroll
      for (int j = 0; j < 4; ++j)
#pragma unroll
        for (int r = 0; r < 4; ++r)
          obf[(quad * 4 + r) * 68 + j * 16 + l15] = acc[i][j][r];
#pragma unroll
      for (int t = 0; t < 2; ++t) {
        const int rr = t * 8 + (lane >> 3);
        const int rowg = tM + wm * 128 + i * 16 + rr;
        const size_t idx = (size_t)rowg * DIM + tN + wn * 64 + ch * 8;
        const float4* rp = (const float4*)&obf[rr * 68 + ch * 8];
        float4 aa = rp[0], bb4 = rp[1];
        float f[8] = {aa.x, aa.y, aa.z, aa.w, bb4.x, bb4.y, bb4.z, bb4.w};
        if constexpr (MODE == 3) {
          bf16x8 xv = *(const bf16x8*)(Xb + idx);
#pragma unroll
          for (int u = 0; u < 8; ++u) f[u] += (float)xv[u];
        } else {
          const float4* op = (const float4*)(Of + idx);
          float4 oa = op[0], ob4 = op[1];
          f[0] += oa.x; f[1] += oa.y; f[2] += oa.z; f[3] += oa.w;
          f[4] += ob4.x; f[5] += ob4.y; f[6] += ob4.z; f[7] += ob4.w;
        }
        float4 o0 = {f[0], f[1], f[2], f[3]}, o1 = {f[4], f[5], f[6], f[7]};
        ((float4*)(Of + idx))[0] = o0;
        ((float4*)(Of + idx))[1] = o1;
      }
    }
    return;
  }
}

// ---------------- windowed attention: one block per (b,h,window) ----------------
__global__ __launch_bounds__(256, 3) void attn_kernel(const bf16* __restrict__ q,
                                                      const bf16* __restrict__ k,
                                                      const bf16* __restrict__ v,
                                                      bf16* __restrict__ ao) {
  __shared__ __align__(16) bf16 kv[256 * 72];       // K [tok][72]; later V^T [d][264]
  __shared__ __align__(16) bf16 pbuf[4][16 * 136];  // per-wave half-P / O tile
  const int w = blockIdx.x, h = blockIdx.y, b = blockIdx.z;
  const int tid = threadIdx.x;
  const int wv = tid >> 6, lane = tid & 63;
  const int l15 = lane & 15, quad = lane >> 4;
  const size_t bh = (size_t)b * HEADS + h;
  const bf16* qb = q + bh * SEQ * DH;
  const bf16* kb = k + bh * SEQ * DH;
  const bf16* vb = v + bh * SEQ * DH;
  const int t0 = (w - 1) * WIN;                     // tile token range [t0, t0+256)

#pragma unroll
  for (int it = 0; it < 8; ++it) {
    const int c = it * 256 + tid;
    const int tok = c >> 3, ch = c & 7;
    int gt = t0 + tok; gt = gt < 0 ? 0 : gt;
    *(bf16x8*)&kv[tok * 72 + ch * 8] = *(const bf16x8*)(kb + (size_t)gt * DH + ch * 8);
  }
  bf16x8 aQ[2][2];
#pragma unroll
  for (int qt = 0; qt < 2; ++qt) {
    const int qtok = w * WIN + wv * 32 + qt * 16 + l15;
#pragma unroll
    for (int ks = 0; ks < 2; ++ks)
      aQ[qt][ks] = *(const bf16x8*)(qb + (size_t)qtok * DH + ks * 32 + quad * 8);
  }
  int gtv = t0 + tid; gtv = gtv < 0 ? 0 : gtv;
  bf16x8 vld[8];
#pragma unroll
  for (int dg = 0; dg < 8; ++dg)
    vld[dg] = *(const bf16x8*)(vb + (size_t)gtv * DH + dg * 8);
  __syncthreads();

  bf16x8 aP[2][8];
#pragma unroll
  for (int qt = 0; qt < 2; ++qt) {
    f32x4 sreg[16];
#pragma unroll
    for (int nt = 0; nt < 16; ++nt) {
      f32x4 a = {0.f, 0.f, 0.f, 0.f};
#pragma unroll
      for (int ks = 0; ks < 2; ++ks) {
        bf16x8 bK = *(const bf16x8*)&kv[(nt * 16 + l15) * 72 + ks * 32 + quad * 8];
        a = mfma16(aQ[qt][ks], bK, a);
      }
      sreg[nt] = a;
    }
    const int qlb = wv * 32 + qt * 16 + quad * 4;
    float rinv[4];
#pragma unroll
    for (int r = 0; r < 4; ++r) {
      const int ql = qlb + r;
      float sum = 0.f;
#pragma unroll
      for (int nt = 0; nt < 16; ++nt) {
        const int j = nt * 16 + l15;
        const bool valid = (nt < 8) ? (w > 0) : (ql >= j - WIN);
        const float p = valid ? __expf(sreg[nt][r]) : 0.0f;   // no max-sub: |s|<=8
        sreg[nt][r] = p;
        sum += p;
      }
#pragma unroll
      for (int m = 8; m; m >>= 1) sum += __shfl_xor(sum, m);
      rinv[r] = 1.0f / sum;
    }
#pragma unroll
    for (int half = 0; half < 2; ++half) {
#pragma unroll
      for (int ntw = 0; ntw < 8; ++ntw)
#pragma unroll
        for (int r = 0; r < 4; ++r)
          pbuf[wv][(quad * 4 + r) * 136 + ntw * 16 + l15] =
              (bf16)(sreg[half * 8 + ntw][r] * rinv[r]);
#pragma unroll
      for (int kk = 0; kk < 4; ++kk)
        aP[qt][half * 4 + kk] = *(const bf16x8*)&pbuf[wv][l15 * 136 + kk * 32 + quad * 8];
    }
  }
  __syncthreads();

#pragma unroll
  for (int dg = 0; dg < 8; ++dg)
#pragma unroll
    for (int i = 0; i < 8; ++i)
      kv[(dg * 8 + i) * 264 + tid] = vld[dg][i];
  __syncthreads();

#pragma unroll
  for (int qt = 0; qt < 2; ++qt) {
#pragma unroll
    for (int dt = 0; dt < 4; ++dt) {
      f32x4 o = {0.f, 0.f, 0.f, 0.f};
#pragma unroll
      for (int ks2 = 0; ks2 < 8; ++ks2) {
        bf16x8 bV = *(const bf16x8*)&kv[(dt * 16 + l15) * 264 + ks2 * 32 + quad * 8];
        o = mfma16(aP[qt][ks2], bV, o);
      }
#pragma unroll
      for (int r = 0; r < 4; ++r)
        pbuf[wv][(quad * 4 + r) * 136 + dt * 16 + l15] = (bf16)o[r];
    }
#pragma unroll
    for (int t = 0; t < 2; ++t) {
      const int rr = t * 8 + (lane >> 3), ch = lane & 7;
      bf16x8 ov = *(const bf16x8*)&pbuf[wv][rr * 136 + ch * 8];
      const int tok = w * WIN + wv * 32 + qt * 16 + rr;
      *(bf16x8*)(ao + ((size_t)b * SEQ + tok) * DIM + h * DH + ch * 8) = ov;
    }
  }
}

extern "C" void kernel_launch(void* const* d_in, const int* in_sizes, int n_in,
                              void* d_out, int out_size, void* d_ws, size_t ws_size,
                              hipStream_t stream) {
  (void)in_sizes; (void)n_in; (void)out_size;
  float* out = (float*)d_out;                      // fp32 output per reference dtype
  bf16* cano = (bf16*)d_ws;
  const unsigned short* probe = (const unsigned short*)d_in[2];

  SrcPtrs sp;
  for (int i = 0; i < 12; ++i) sp.p[i] = d_in[i];

  bf16* slot0 = cano + P_EL;             // h -> ao -> hf
  bf16* slot1 = cano + P_EL + R_EL;      // q -> x2
  bf16* slot2 = cano + P_EL + 2 * R_EL;  // k ; later f1
  bf16* slot3 = cano + P_EL + 3 * R_EL;  // v (natural head-major layout)

  const bf16* qsc  = cano + C_SM + 0;
  const bf16* ksc  = cano + C_SM + 64;
  const bf16* bout = cano + C_SM + 128;
  const bf16* l1g  = cano + C_SM + 640;
  const bf16* l1b  = cano + C_SM + 1152;
  const bf16* lfg  = cano + C_SM + 1664;
  const bf16* lfb  = cano + C_SM + 2176;

  constexpr int LDS8 = 131072;           // 128 KiB dynamic LDS for gemm8
  static bool attr_done = false;
  if (!attr_done) {
    hipFuncSetAttribute((const void*)gemm8<0>, hipFuncAttributeMaxDynamicSharedMemorySize, LDS8);
    hipFuncSetAttribute((const void*)gemm8<1>, hipFuncAttributeMaxDynamicSharedMemorySize, LDS8);
    hipFuncSetAttribute((const void*)gemm8<2>, hipFuncAttributeMaxDynamicSharedMemorySize, LDS8);
    hipFuncSetAttribute((const void*)gemm8<3>, hipFuncAttributeMaxDynamicSharedMemorySize, LDS8);
    hipFuncSetAttribute((const void*)gemm8<4>, hipFuncAttributeMaxDynamicSharedMemorySize, LDS8);
    attr_done = true;
  }

  ingest_kernel<<<1538, 256, 0, stream>>>(sp, cano);
  ln_kernel<<<TOK / 4, 256, 0, stream>>>(d_in[0], l1g, l1b, slot0, probe, 1);
  gemm8<0><<<128 * 6, 512, LDS8, stream>>>(slot0, cano + C_QKV, slot1, slot2, slot3,
                                           nullptr, nullptr, qsc, ksc, probe,
                                           DIM, DIM, 0, 6);
  attn_kernel<<<dim3(NW, HEADS, BATCH), 256, 0, stream>>>(slot1, slot2, slot3, slot0);
  gemm8<1><<<128 * 2, 512, LDS8, stream>>>(slot0, cano + C_WOUT, slot1, nullptr, nullptr,
                                           nullptr, d_in[0], nullptr, bout, probe,
                                           DIM, DIM, 0, 2);
  ln_kernel<<<TOK / 4, 256, 0, stream>>>(slot1, lfg, lfb, slot0, probe, 0);

  const bool big = ws_size >= (size_t)(P_EL + 6 * R_EL) * 2;
  if (big) {
    bf16* f1 = slot2;                    // spans slot2..slot5 (4R)
    gemm8<2><<<128 * 8, 512, LDS8, stream>>>(slot0, cano + C_WF1, f1, nullptr, nullptr,
                                             nullptr, nullptr, nullptr, nullptr, probe,
                                             DIM, DIM, 2048, 8);
    gemm8<3><<<128 * 2, 512, LDS8, stream>>>(f1, cano + C_WF2, nullptr, nullptr, nullptr,
                                             out, nullptr, slot1, nullptr, probe,
                                             2048, 2048, 0, 2);
  } else {
    bf16* f1h = slot2;                   // TOK x 1024 bf16 = 2R
    for (int half = 0; half < 2; ++half) {
      const bf16* w1h = cano + C_WF1 + (size_t)half * 1024 * DIM;
      const bf16* w2h = cano + C_WF2 + (size_t)half * 1024;
      gemm8<2><<<128 * 4, 512, LDS8, stream>>>(slot0, w1h, f1h, nullptr, nullptr,
                                               nullptr, nullptr, nullptr, nullptr, probe,
                                               DIM, DIM, 1024, 4);
      if (half == 0)
        gemm8<3><<<128 * 2, 512, LDS8, stream>>>(f1h, w2h, nullptr, nullptr, nullptr,
                                                 out, nullptr, slot1, nullptr, probe,
                                                 1024, 2048, 0, 2);
      else
        gemm8<4><<<128 * 2, 512, LDS8, stream>>>(f1h, w2h, nullptr, nullptr, nullptr,
                                                 out, nullptr, nullptr, nullptr, probe,
                                                 1024, 2048, 0, 2);
    }
  }
}

// Round 3
// 509.915 us; speedup vs baseline: 1.1293x; 1.1293x over previous
//
#include <hip/hip_runtime.h>
#include <cstdint>
#include <cstddef>

typedef __bf16 bf16;
typedef __bf16 bf16x8 __attribute__((ext_vector_type(8)));
typedef float f32x4 __attribute__((ext_vector_type(4)));

#define DEV static __device__ __forceinline__

constexpr int BATCH = 8;
constexpr int SEQ = 4096;
constexpr int DIM = 512;
constexpr int HEADS = 8;
constexpr int DH = 64;
constexpr int WIN = 128;
constexpr int NW = SEQ / WIN;        // 32
constexpr int TOK = BATCH * SEQ;     // 32768
constexpr float EPS = 1e-5f;

// canonical bf16 weights in workspace (element offsets)
constexpr size_t R_EL   = (size_t)TOK * DIM;            // 16,777,216
constexpr size_t C_QKV  = 0;                             // 786432
constexpr size_t C_WOUT = 786432;                        // 262144
constexpr size_t C_WF1  = 1048576;                       // 1048576
constexpr size_t C_WF2  = 2097152;                       // 1048576
constexpr size_t C_SM   = 3145728;                       // 2688 smalls
// smalls: qsc 0, ksc 64, bout 128, l1g 640, l1b 1152, lfg 1664, lfb 2176
constexpr size_t P_EL   = 3148416;                       // slot base (%8==0)

DEV void gload_lds16(const void* g, void* l) {
  __builtin_amdgcn_global_load_lds((__attribute__((address_space(1))) void*)g,
                                   (__attribute__((address_space(3))) void*)l,
                                   16, 0, 0);
}

DEV f32x4 mfma16(bf16x8 a, bf16x8 b, f32x4 c) {
  return __builtin_amdgcn_mfma_f32_16x16x32_bf16(a, b, c, 0, 0, 0);
}

// Branchless exact-GELU via Abramowitz-Stegun 7.1.26 erf approximation.
// |erf error| <= 1.5e-7 (far below bf16 output rounding). ~16 cheap VALU ops,
// no divergence -- vs library erff's two-path implementation.
DEV float fast_gelu(float v) {
  const float z = fabsf(v) * 0.7071067811865476f;
  const float t = __builtin_amdgcn_rcpf(1.0f + 0.3275911f * z);
  const float p = t * (0.254829592f +
                  t * (-0.284496736f +
                  t * (1.421413741f +
                  t * (-1.453152027f +
                  t * 1.061405429f))));
  const float e = __expf(-z * z);
  const float erfa = 1.0f - p * e;               // erf(|v|/sqrt2)
  const float cdf = 0.5f + copysignf(0.5f * erfa, v);
  return v * cdf;
}

// ---------------- ingest: dtype-probe + convert weight inputs to bf16 ----------
struct SrcPtrs { const void* p[12]; };

DEV void copy8(const void* src, long si, bf16* dst, bool f32) {
  if (f32) {
    const float4* s = (const float4*)((const float*)src + si);
    float4 a = s[0], b = s[1];
    bf16x8 o;
    o[0] = (bf16)a.x; o[1] = (bf16)a.y; o[2] = (bf16)a.z; o[3] = (bf16)a.w;
    o[4] = (bf16)b.x; o[5] = (bf16)b.y; o[6] = (bf16)b.z; o[7] = (bf16)b.w;
    *(bf16x8*)dst = o;
  } else {
    *(bf16x8*)dst = *(const bf16x8*)((const bf16*)src + si);
  }
}

__global__ __launch_bounds__(256) void ingest_kernel(SrcPtrs sp, bf16* cano) {
  const bool f32 = (((const unsigned short*)sp.p[2])[0] == 0);
  const long e = (long)threadIdx.x * 8;
  int b = blockIdx.x;
  if (b < 384)  { long o = (long)b * 2048 + e; copy8(sp.p[1], o, cano + C_QKV + o, f32); return; }
  b -= 384;
  if (b < 128)  { long o = (long)b * 2048 + e; copy8(sp.p[4], o, cano + C_WOUT + o, f32); return; }
  b -= 128;
  if (b < 512)  { long o = (long)b * 2048 + e; copy8(sp.p[10], o, cano + C_WF1 + o, f32); return; }
  b -= 512;
  if (b < 512)  { long o = (long)b * 2048 + e; copy8(sp.p[11], o, cano + C_WF2 + o, f32); return; }
  b -= 512;
  const long o = (long)b * 2048 + e;
  if (o >= 2688) return;
  const void* src; long si;
  if      (o < 64)   { src = sp.p[2]; si = o; }
  else if (o < 128)  { src = sp.p[3]; si = o - 64; }
  else if (o < 640)  { src = sp.p[5]; si = o - 128; }
  else if (o < 1152) { src = sp.p[6]; si = o - 640; }
  else if (o < 1664) { src = sp.p[7]; si = o - 1152; }
  else if (o < 2176) { src = sp.p[8]; si = o - 1664; }
  else               { src = sp.p[9]; si = o - 2176; }
  copy8(src, si, cano + C_SM + o, f32);
}

// ---------------- LayerNorm: one wave per 512-dim token ----------------
__global__ __launch_bounds__(256) void ln_kernel(const void* __restrict__ in,
                                                 const bf16* __restrict__ gg,
                                                 const bf16* __restrict__ bb,
                                                 bf16* __restrict__ out,
                                                 const unsigned short* __restrict__ probe,
                                                 int raw) {
  const int wave = threadIdx.x >> 6, lane = threadIdx.x & 63;
  const int row = blockIdx.x * 4 + wave;
  const size_t base = (size_t)row * DIM + lane * 8;
  float f[8];
  if (raw && probe[0] == 0) {
    const float4* p = (const float4*)((const float*)in + base);
    float4 a = p[0], bq = p[1];
    f[0] = a.x; f[1] = a.y; f[2] = a.z; f[3] = a.w;
    f[4] = bq.x; f[5] = bq.y; f[6] = bq.z; f[7] = bq.w;
  } else {
    bf16x8 v = *(const bf16x8*)((const bf16*)in + base);
#pragma unroll
    for (int i = 0; i < 8; ++i) f[i] = (float)v[i];
  }
  float s = 0.f, sq = 0.f;
#pragma unroll
  for (int i = 0; i < 8; ++i) { s += f[i]; sq += f[i] * f[i]; }
#pragma unroll
  for (int m = 32; m; m >>= 1) { s += __shfl_xor(s, m); sq += __shfl_xor(sq, m); }
  const float mean = s * (1.0f / DIM);
  const float var = fmaxf(sq * (1.0f / DIM) - mean * mean, 0.0f);
  const float rs = rsqrtf(var + EPS);
  bf16x8 gv = *(const bf16x8*)(gg + lane * 8);
  bf16x8 bv = *(const bf16x8*)(bb + lane * 8);
  bf16x8 o;
#pragma unroll
  for (int i = 0; i < 8; ++i) o[i] = (bf16)((f[i] - mean) * rs * (float)gv[i] + (float)bv[i]);
  *(bf16x8*)((bf16*)out + base) = o;
}

// ---------------- GEMM: C = A(MxK) @ Bw(N x K, row-stride bstride)^T ----------------
// Double-buffered single-barrier K-loop (proven 128^2 structure).
// Epilogues are BARRIER-FREE: K/32 is always even so the final compute phase
// reads buf1 (elements 8192..16383); epilogue restage regions live entirely in
// buf0 (b16 modes: 4 waves x 1152 <= 4608 elems; f32 modes: 4 waves x 1024
// floats = elems 0..8191 exactly), buf0 is quiescent after the last loop-top
// __syncthreads (its last read was fenced there; no staging in flight), and
// regions are per-wave private. Disjoint => no post-loop barrier/drain needed.
// MODE 0: QKV -> q,k,v head-major [bh][n][64]; q/k fused l2norm*scale+rope
// MODE 1: + X(raw x, probe-switched) + bias -> O0 bf16 (stride DIM)
// MODE 2: fast exact gelu -> O0 bf16 (stride ostride)
// MODE 3: + Xb(bf16, stride DIM) -> Of fp32 (stride DIM)
// MODE 4: + Of(read-back fp32)   -> Of fp32 (stride DIM)
template <int MODE>
__global__ __launch_bounds__(256) void gemm_bt(const bf16* __restrict__ A,
                                               const bf16* __restrict__ Bw,
                                               bf16* __restrict__ O0, bf16* __restrict__ O1,
                                               bf16* __restrict__ O2,
                                               float* __restrict__ Of,
                                               const void* __restrict__ Xraw,
                                               const bf16* __restrict__ Xb,
                                               const bf16* __restrict__ bias,
                                               const unsigned short* __restrict__ probe,
                                               int K, int bstride, int ostride, int gx) {
  __shared__ __align__(16) bf16 smem[4 * 128 * 32];   // 32 KB: two (As,Bs) pairs
  const int tid = threadIdx.x;
  const int wave = tid >> 6, lane = tid & 63;
  const int l15 = lane & 15, quad = lane >> 4;
  // XCD-aware swizzle (8 m-strips per XCD group, n fastest within)
  const int id = blockIdx.x;
  const int per = gx * 8;
  const int tM = ((id / per) * 8 + (id & 7)) * 128;
  const int tN = ((id % per) >> 3) * 128;
  const int wM = (wave >> 1) * 64, wN = (wave & 1) * 64;
  f32x4 acc[4][4];
  const f32x4 z = {0.f, 0.f, 0.f, 0.f};
#pragma unroll
  for (int i = 0; i < 4; ++i)
#pragma unroll
    for (int j = 0; j < 4; ++j) acc[i][j] = z;

  auto stage = [&](int k0, int p) {
    bf16* dA = smem + p * 8192;
    bf16* dB = dA + 4096;
#pragma unroll
    for (int t = 0; t < 2; ++t) {
      const int c = tid + t * 256;              // 512 16B-chunks per tile
      const int row = c >> 2, cc = (c & 3) * 8;
      gload_lds16(A + (size_t)(tM + row) * K + k0 + cc, &dA[c * 8]);
      gload_lds16(Bw + (size_t)(tN + row) * bstride + k0 + cc, &dB[c * 8]);
    }
  };

  stage(0, 0);
  int cur = 0;
  for (int k0 = 0; k0 < K; k0 += 32) {
    __syncthreads();                            // drains prefetch of buf[cur]
    if (k0 + 32 < K) stage(k0 + 32, cur ^ 1);   // async into alternate buffer
    const bf16* As = smem + cur * 8192;
    const bf16* Bs = As + 4096;
    bf16x8 aF[4], bF[4];
#pragma unroll
    for (int i = 0; i < 4; ++i) aF[i] = *(const bf16x8*)&As[(wM + i * 16 + l15) * 32 + quad * 8];
#pragma unroll
    for (int j = 0; j < 4; ++j) bF[j] = *(const bf16x8*)&Bs[(wN + j * 16 + l15) * 32 + quad * 8];
#pragma unroll
    for (int i = 0; i < 4; ++i)
#pragma unroll
      for (int j = 0; j < 4; ++j) acc[i][j] = mfma16(aF[i], bF[j], acc[i][j]);
    cur ^= 1;
  }

  if constexpr (MODE == 0) {
    // wave's 64-col span is exactly one (q/k/v, head) plane; fused rope for q/k
    bf16* ob = smem + wave * 1152;              // per-wave 16 x 72 tile (in buf0)
    const int colbase = tN + wN;
    const int which = colbase >> 9;
    const int head = (colbase >> 6) & 7;
    bf16* dst = which == 0 ? O0 : (which == 1 ? O1 : O2);
    const int ch = lane & 7;
    float scv[8], invf[8];
    if (which < 2) {
      const bf16* sc = which ? bias : Xb;       // ksc : qsc
      bf16x8 s8 = *(const bf16x8*)(sc + ch * 8);
#pragma unroll
      for (int u = 0; u < 8; ++u) {
        scv[u] = (float)s8[u] * (which == 0 ? 8.0f : 1.0f);   // fold QK_SCALE into q
        invf[u] = exp2f(-(float)((ch & 3) * 8 + u) * (13.287712379549449f / 32.0f));
      }
    }
#pragma unroll
    for (int i = 0; i < 4; ++i) {
#pragma unroll
      for (int j = 0; j < 4; ++j)
#pragma unroll
        for (int r = 0; r < 4; ++r)
          ob[(quad * 4 + r) * 72 + j * 16 + l15] = (bf16)acc[i][j][r];
#pragma unroll
      for (int t = 0; t < 2; ++t) {
        const int rr = t * 8 + (lane >> 3);
        const int rowg = tM + wM + i * 16 + rr;
        bf16x8 ov = *(const bf16x8*)&ob[rr * 72 + ch * 8];
        float f[8];
#pragma unroll
        for (int u = 0; u < 8; ++u) f[u] = (float)ov[u];
        if (which < 2) {
          float ss = 0.f;
#pragma unroll
          for (int u = 0; u < 8; ++u) ss += f[u] * f[u];
          ss += __shfl_xor(ss, 1); ss += __shfl_xor(ss, 2); ss += __shfl_xor(ss, 4);
          const float rs = 1.0f / fmaxf(sqrtf(ss), 1e-12f);
#pragma unroll
          for (int u = 0; u < 8; ++u) f[u] *= rs * scv[u];
          float pf[8];
#pragma unroll
          for (int u = 0; u < 8; ++u) pf[u] = __shfl_xor(f[u], 4);
          const float pos = (float)(rowg & (SEQ - 1));
#pragma unroll
          for (int u = 0; u < 8; ++u) {
            float sn, cs;
            __sincosf(pos * invf[u], &sn, &cs);
            const float rot = (ch < 4) ? -pf[u] : pf[u];
            f[u] = f[u] * cs + rot * sn;
          }
        }
        bf16x8 o8;
#pragma unroll
        for (int u = 0; u < 8; ++u) o8[u] = (bf16)f[u];
        const int bb = rowg >> 12, n = rowg & (SEQ - 1);
        *(bf16x8*)(dst + ((size_t)(bb * HEADS + head) * SEQ + n) * DH + ch * 8) = o8;
      }
    }
    return;
  }

  if constexpr (MODE == 1 || MODE == 2) {
    // coalesced epilogue via per-wave LDS restage (barrier-free; region in buf0)
    bf16* ob = smem + wave * 1152;              // 16 x 72
    const int ch = lane & 7;
    bf16x8 bias8;
    bool xf32 = false;
    if constexpr (MODE == 1) {
      bias8 = *(const bf16x8*)(bias + tN + wN + ch * 8);
      xf32 = (probe[0] == 0);
    }
#pragma unroll
    for (int i = 0; i < 4; ++i) {
#pragma unroll
      for (int j = 0; j < 4; ++j)
#pragma unroll
        for (int r = 0; r < 4; ++r)
          ob[(quad * 4 + r) * 72 + j * 16 + l15] = (bf16)acc[i][j][r];
#pragma unroll
      for (int t = 0; t < 2; ++t) {
        const int rr = t * 8 + (lane >> 3);
        const int rowg = tM + wM + i * 16 + rr;
        bf16x8 ov = *(const bf16x8*)&ob[rr * 72 + ch * 8];
        bf16x8 o8;
        if constexpr (MODE == 1) {
          const size_t idx = (size_t)rowg * DIM + tN + wN + ch * 8;
          float xr[8];
          if (xf32) {
            const float4* xp = (const float4*)((const float*)Xraw + idx);
            float4 a = xp[0], bq = xp[1];
            xr[0] = a.x; xr[1] = a.y; xr[2] = a.z; xr[3] = a.w;
            xr[4] = bq.x; xr[5] = bq.y; xr[6] = bq.z; xr[7] = bq.w;
          } else {
            bf16x8 xv = *(const bf16x8*)((const bf16*)Xraw + idx);
#pragma unroll
            for (int u = 0; u < 8; ++u) xr[u] = (float)xv[u];
          }
#pragma unroll
          for (int u = 0; u < 8; ++u) o8[u] = (bf16)((float)ov[u] + xr[u] + (float)bias8[u]);
          *(bf16x8*)(O0 + idx) = o8;
        } else {
#pragma unroll
          for (int u = 0; u < 8; ++u) o8[u] = (bf16)fast_gelu((float)ov[u]);
          *(bf16x8*)(O0 + (size_t)rowg * ostride + tN + wN + ch * 8) = o8;
        }
      }
    }
    return;
  }

  if constexpr (MODE == 3 || MODE == 4) {
    // fp32 LDS restage -> float4 stores (barrier-free; 4 waves x 1024 floats
    // = bf16 elems 0..8191 = exactly buf0)
    float* obf = (float*)smem + wave * 1024;    // 16 x 64 floats
    const int ch = lane & 7;
#pragma unroll
    for (int i = 0; i < 4; ++i) {
#pragma unroll
      for (int j = 0; j < 4; ++j)
#pragma unroll
        for (int r = 0; r < 4; ++r)
          obf[(quad * 4 + r) * 64 + j * 16 + l15] = acc[i][j][r];
#pragma unroll
      for (int t = 0; t < 2; ++t) {
        const int rr = t * 8 + (lane >> 3);
        const int rowg = tM + wM + i * 16 + rr;
        const size_t idx = (size_t)rowg * DIM + tN + wN + ch * 8;
        const float4* rp = (const float4*)&obf[rr * 64 + ch * 8];
        float4 a = rp[0], b = rp[1];
        float f[8] = {a.x, a.y, a.z, a.w, b.x, b.y, b.z, b.w};
        if constexpr (MODE == 3) {
          bf16x8 xv = *(const bf16x8*)(Xb + idx);
#pragma unroll
          for (int u = 0; u < 8; ++u) f[u] += (float)xv[u];
        } else {
          const float4* op = (const float4*)(Of + idx);
          float4 oa = op[0], ob4 = op[1];
          f[0] += oa.x; f[1] += oa.y; f[2] += oa.z; f[3] += oa.w;
          f[4] += ob4.x; f[5] += ob4.y; f[6] += ob4.z; f[7] += ob4.w;
        }
        float4 o0 = {f[0], f[1], f[2], f[3]}, o1 = {f[4], f[5], f[6], f[7]};
        ((float4*)(Of + idx))[0] = o0;
        ((float4*)(Of + idx))[1] = o1;
      }
    }
    return;
  }
}

// ---------------- windowed attention: one block per (b,h,window) ----------------
__global__ __launch_bounds__(256, 3) void attn_kernel(const bf16* __restrict__ q,
                                                      const bf16* __restrict__ k,
                                                      const bf16* __restrict__ v,
                                                      bf16* __restrict__ ao) {
  __shared__ __align__(16) bf16 kv[256 * 72];       // K [tok][72]; later V^T [d][264]
  __shared__ __align__(16) bf16 pbuf[4][16 * 136];  // per-wave half-P / O tile
  const int w = blockIdx.x, h = blockIdx.y, b = blockIdx.z;
  const int tid = threadIdx.x;
  const int wv = tid >> 6, lane = tid & 63;
  const int l15 = lane & 15, quad = lane >> 4;
  const size_t bh = (size_t)b * HEADS + h;
  const bf16* qb = q + bh * SEQ * DH;
  const bf16* kb = k + bh * SEQ * DH;
  const bf16* vb = v + bh * SEQ * DH;
  const int t0 = (w - 1) * WIN;                     // tile token range [t0, t0+256)

#pragma unroll
  for (int it = 0; it < 8; ++it) {
    const int c = it * 256 + tid;
    const int tok = c >> 3, ch = c & 7;
    int gt = t0 + tok; gt = gt < 0 ? 0 : gt;
    *(bf16x8*)&kv[tok * 72 + ch * 8] = *(const bf16x8*)(kb + (size_t)gt * DH + ch * 8);
  }
  bf16x8 aQ[2][2];
#pragma unroll
  for (int qt = 0; qt < 2; ++qt) {
    const int qtok = w * WIN + wv * 32 + qt * 16 + l15;
#pragma unroll
    for (int ks = 0; ks < 2; ++ks)
      aQ[qt][ks] = *(const bf16x8*)(qb + (size_t)qtok * DH + ks * 32 + quad * 8);
  }
  int gtv = t0 + tid; gtv = gtv < 0 ? 0 : gtv;
  bf16x8 vld[8];
#pragma unroll
  for (int dg = 0; dg < 8; ++dg)
    vld[dg] = *(const bf16x8*)(vb + (size_t)gtv * DH + dg * 8);
  __syncthreads();

  bf16x8 aP[2][8];
#pragma unroll
  for (int qt = 0; qt < 2; ++qt) {
    f32x4 sreg[16];
#pragma unroll
    for (int nt = 0; nt < 16; ++nt) {
      f32x4 a = {0.f, 0.f, 0.f, 0.f};
#pragma unroll
      for (int ks = 0; ks < 2; ++ks) {
        bf16x8 bK = *(const bf16x8*)&kv[(nt * 16 + l15) * 72 + ks * 32 + quad * 8];
        a = mfma16(aQ[qt][ks], bK, a);
      }
      sreg[nt] = a;
    }
    const int qlb = wv * 32 + qt * 16 + quad * 4;
    float rinv[4];
#pragma unroll
    for (int r = 0; r < 4; ++r) {
      const int ql = qlb + r;
      float sum = 0.f;
#pragma unroll
      for (int nt = 0; nt < 16; ++nt) {
        const int j = nt * 16 + l15;
        const bool valid = (nt < 8) ? (w > 0) : (ql >= j - WIN);
        const float p = valid ? __expf(sreg[nt][r]) : 0.0f;   // no max-sub: |s|<=8
        sreg[nt][r] = p;
        sum += p;
      }
#pragma unroll
      for (int m = 8; m; m >>= 1) sum += __shfl_xor(sum, m);
      rinv[r] = 1.0f / sum;
    }
#pragma unroll
    for (int half = 0; half < 2; ++half) {
#pragma unroll
      for (int ntw = 0; ntw < 8; ++ntw)
#pragma unroll
        for (int r = 0; r < 4; ++r)
          pbuf[wv][(quad * 4 + r) * 136 + ntw * 16 + l15] =
              (bf16)(sreg[half * 8 + ntw][r] * rinv[r]);
#pragma unroll
      for (int kk = 0; kk < 4; ++kk)
        aP[qt][half * 4 + kk] = *(const bf16x8*)&pbuf[wv][l15 * 136 + kk * 32 + quad * 8];
    }
  }
  __syncthreads();

#pragma unroll
  for (int dg = 0; dg < 8; ++dg)
#pragma unroll
    for (int i = 0; i < 8; ++i)
      kv[(dg * 8 + i) * 264 + tid] = vld[dg][i];
  __syncthreads();

#pragma unroll
  for (int qt = 0; qt < 2; ++qt) {
#pragma unroll
    for (int dt = 0; dt < 4; ++dt) {
      f32x4 o = {0.f, 0.f, 0.f, 0.f};
#pragma unroll
      for (int ks2 = 0; ks2 < 8; ++ks2) {
        bf16x8 bV = *(const bf16x8*)&kv[(dt * 16 + l15) * 264 + ks2 * 32 + quad * 8];
        o = mfma16(aP[qt][ks2], bV, o);
      }
#pragma unroll
      for (int r = 0; r < 4; ++r)
        pbuf[wv][(quad * 4 + r) * 136 + dt * 16 + l15] = (bf16)o[r];
    }
#pragma unroll
    for (int t = 0; t < 2; ++t) {
      const int rr = t * 8 + (lane >> 3), ch = lane & 7;
      bf16x8 ov = *(const bf16x8*)&pbuf[wv][rr * 136 + ch * 8];
      const int tok = w * WIN + wv * 32 + qt * 16 + rr;
      *(bf16x8*)(ao + ((size_t)b * SEQ + tok) * DIM + h * DH + ch * 8) = ov;
    }
  }
}

extern "C" void kernel_launch(void* const* d_in, const int* in_sizes, int n_in,
                              void* d_out, int out_size, void* d_ws, size_t ws_size,
                              hipStream_t stream) {
  (void)in_sizes; (void)n_in; (void)out_size;
  float* out = (float*)d_out;                      // fp32 output per reference dtype
  bf16* cano = (bf16*)d_ws;
  const unsigned short* probe = (const unsigned short*)d_in[2];

  SrcPtrs sp;
  for (int i = 0; i < 12; ++i) sp.p[i] = d_in[i];

  bf16* slot0 = cano + P_EL;             // h -> ao -> hf
  bf16* slot1 = cano + P_EL + R_EL;      // q -> x2
  bf16* slot2 = cano + P_EL + 2 * R_EL;  // k ; later f1
  bf16* slot3 = cano + P_EL + 3 * R_EL;  // v (natural head-major layout)

  const bf16* qsc  = cano + C_SM + 0;
  const bf16* ksc  = cano + C_SM + 64;
  const bf16* bout = cano + C_SM + 128;
  const bf16* l1g  = cano + C_SM + 640;
  const bf16* l1b  = cano + C_SM + 1152;
  const bf16* lfg  = cano + C_SM + 1664;
  const bf16* lfb  = cano + C_SM + 2176;

  ingest_kernel<<<1538, 256, 0, stream>>>(sp, cano);
  ln_kernel<<<TOK / 4, 256, 0, stream>>>(d_in[0], l1g, l1b, slot0, probe, 1);
  gemm_bt<0><<<12 * 256, 256, 0, stream>>>(slot0, cano + C_QKV, slot1, slot2, slot3,
                                           nullptr, nullptr, qsc, ksc, probe,
                                           DIM, DIM, 0, 12);
  attn_kernel<<<dim3(NW, HEADS, BATCH), 256, 0, stream>>>(slot1, slot2, slot3, slot0);
  gemm_bt<1><<<4 * 256, 256, 0, stream>>>(slot0, cano + C_WOUT, slot1, nullptr, nullptr,
                                          nullptr, d_in[0], nullptr, bout, probe,
                                          DIM, DIM, 0, 4);
  ln_kernel<<<TOK / 4, 256, 0, stream>>>(slot1, lfg, lfb, slot0, probe, 0);

  const bool big = ws_size >= (size_t)(P_EL + 6 * R_EL) * 2;
  if (big) {
    bf16* f1 = slot2;                    // spans slot2..slot5 (4R)
    gemm_bt<2><<<16 * 256, 256, 0, stream>>>(slot0, cano + C_WF1, f1, nullptr, nullptr,
                                             nullptr, nullptr, nullptr, nullptr, probe,
                                             DIM, DIM, 2048, 16);
    gemm_bt<3><<<4 * 256, 256, 0, stream>>>(f1, cano + C_WF2, nullptr, nullptr, nullptr,
                                            out, nullptr, slot1, nullptr, probe,
                                            2048, 2048, 0, 4);
  } else {
    bf16* f1h = slot2;                   // TOK x 1024 bf16 = 2R
    for (int half = 0; half < 2; ++half) {
      const bf16* w1h = cano + C_WF1 + (size_t)half * 1024 * DIM;
      const bf16* w2h = cano + C_WF2 + (size_t)half * 1024;
      gemm_bt<2><<<8 * 256, 256, 0, stream>>>(slot0, w1h, f1h, nullptr, nullptr,
                                              nullptr, nullptr, nullptr, nullptr, probe,
                                              DIM, DIM, 1024, 8);
      if (half == 0)
        gemm_bt<3><<<4 * 256, 256, 0, stream>>>(f1h, w2h, nullptr, nullptr, nullptr,
                                                out, nullptr, slot1, nullptr, probe,
                                                1024, 2048, 0, 4);
      else
        gemm_bt<4><<<4 * 256, 256, 0, stream>>>(f1h, w2h, nullptr, nullptr, nullptr,
                                                out, nullptr, nullptr, nullptr, probe,
                                                1024, 2048, 0, 4);
    }
  }
}

// Round 4
// 505.855 us; speedup vs baseline: 1.1383x; 1.0080x over previous
//
#include <hip/hip_runtime.h>
#include <cstdint>
#include <cstddef>

typedef __bf16 bf16;
typedef __bf16 bf16x8 __attribute__((ext_vector_type(8)));
typedef float f32x4 __attribute__((ext_vector_type(4)));

#define DEV static __device__ __forceinline__

constexpr int BATCH = 8;
constexpr int SEQ = 4096;
constexpr int DIM = 512;
constexpr int HEADS = 8;
constexpr int DH = 64;
constexpr int WIN = 128;
constexpr int NW = SEQ / WIN;        // 32
constexpr int TOK = BATCH * SEQ;     // 32768
constexpr float EPS = 1e-5f;

// canonical bf16 weights in workspace (element offsets)
constexpr size_t R_EL   = (size_t)TOK * DIM;            // 16,777,216
constexpr size_t C_QKV  = 0;                             // 786432
constexpr size_t C_WOUT = 786432;                        // 262144
constexpr size_t C_WF1  = 1048576;                       // 1048576
constexpr size_t C_WF2  = 2097152;                       // 1048576
constexpr size_t C_SM   = 3145728;                       // 2688 smalls
// smalls: qsc 0, ksc 64, bout 128, l1g 640, l1b 1152, lfg 1664, lfb 2176
constexpr size_t P_EL   = 3148416;                       // slot base (%8==0)

DEV void gload_lds16(const void* g, void* l) {
  __builtin_amdgcn_global_load_lds((__attribute__((address_space(1))) void*)g,
                                   (__attribute__((address_space(3))) void*)l,
                                   16, 0, 0);
}

DEV f32x4 mfma16(bf16x8 a, bf16x8 b, f32x4 c) {
  return __builtin_amdgcn_mfma_f32_16x16x32_bf16(a, b, c, 0, 0, 0);
}

// Branchless exact-GELU via Abramowitz-Stegun 7.1.26 erf approximation.
// |erf error| <= 1.5e-7 (far below bf16 output rounding). ~16 cheap VALU ops,
// no divergence -- vs library erff's two-path implementation.
DEV float fast_gelu(float v) {
  const float z = fabsf(v) * 0.7071067811865476f;
  const float t = __builtin_amdgcn_rcpf(1.0f + 0.3275911f * z);
  const float p = t * (0.254829592f +
                  t * (-0.284496736f +
                  t * (1.421413741f +
                  t * (-1.453152027f +
                  t * 1.061405429f))));
  const float e = __expf(-z * z);
  const float erfa = 1.0f - p * e;               // erf(|v|/sqrt2)
  const float cdf = 0.5f + copysignf(0.5f * erfa, v);
  return v * cdf;
}

// ---------------- ingest: dtype-probe + convert weight inputs to bf16 ----------
struct SrcPtrs { const void* p[12]; };

DEV void copy8(const void* src, long si, bf16* dst, bool f32) {
  if (f32) {
    const float4* s = (const float4*)((const float*)src + si);
    float4 a = s[0], b = s[1];
    bf16x8 o;
    o[0] = (bf16)a.x; o[1] = (bf16)a.y; o[2] = (bf16)a.z; o[3] = (bf16)a.w;
    o[4] = (bf16)b.x; o[5] = (bf16)b.y; o[6] = (bf16)b.z; o[7] = (bf16)b.w;
    *(bf16x8*)dst = o;
  } else {
    *(bf16x8*)dst = *(const bf16x8*)((const bf16*)src + si);
  }
}

__global__ __launch_bounds__(256) void ingest_kernel(SrcPtrs sp, bf16* cano) {
  const bool f32 = (((const unsigned short*)sp.p[2])[0] == 0);
  const long e = (long)threadIdx.x * 8;
  int b = blockIdx.x;
  if (b < 384)  { long o = (long)b * 2048 + e; copy8(sp.p[1], o, cano + C_QKV + o, f32); return; }
  b -= 384;
  if (b < 128)  { long o = (long)b * 2048 + e; copy8(sp.p[4], o, cano + C_WOUT + o, f32); return; }
  b -= 128;
  if (b < 512)  { long o = (long)b * 2048 + e; copy8(sp.p[10], o, cano + C_WF1 + o, f32); return; }
  b -= 512;
  if (b < 512)  { long o = (long)b * 2048 + e; copy8(sp.p[11], o, cano + C_WF2 + o, f32); return; }
  b -= 512;
  const long o = (long)b * 2048 + e;
  if (o >= 2688) return;
  const void* src; long si;
  if      (o < 64)   { src = sp.p[2]; si = o; }
  else if (o < 128)  { src = sp.p[3]; si = o - 64; }
  else if (o < 640)  { src = sp.p[5]; si = o - 128; }
  else if (o < 1152) { src = sp.p[6]; si = o - 640; }
  else if (o < 1664) { src = sp.p[7]; si = o - 1152; }
  else if (o < 2176) { src = sp.p[8]; si = o - 1664; }
  else               { src = sp.p[9]; si = o - 2176; }
  copy8(src, si, cano + C_SM + o, f32);
}

// ---------------- LayerNorm: one wave per 512-dim token ----------------
__global__ __launch_bounds__(256) void ln_kernel(const void* __restrict__ in,
                                                 const bf16* __restrict__ gg,
                                                 const bf16* __restrict__ bb,
                                                 bf16* __restrict__ out,
                                                 const unsigned short* __restrict__ probe,
                                                 int raw) {
  const int wave = threadIdx.x >> 6, lane = threadIdx.x & 63;
  const int row = blockIdx.x * 4 + wave;
  const size_t base = (size_t)row * DIM + lane * 8;
  float f[8];
  if (raw && probe[0] == 0) {
    const float4* p = (const float4*)((const float*)in + base);
    float4 a = p[0], bq = p[1];
    f[0] = a.x; f[1] = a.y; f[2] = a.z; f[3] = a.w;
    f[4] = bq.x; f[5] = bq.y; f[6] = bq.z; f[7] = bq.w;
  } else {
    bf16x8 v = *(const bf16x8*)((const bf16*)in + base);
#pragma unroll
    for (int i = 0; i < 8; ++i) f[i] = (float)v[i];
  }
  float s = 0.f, sq = 0.f;
#pragma unroll
  for (int i = 0; i < 8; ++i) { s += f[i]; sq += f[i] * f[i]; }
#pragma unroll
  for (int m = 32; m; m >>= 1) { s += __shfl_xor(s, m); sq += __shfl_xor(sq, m); }
  const float mean = s * (1.0f / DIM);
  const float var = fmaxf(sq * (1.0f / DIM) - mean * mean, 0.0f);
  const float rs = rsqrtf(var + EPS);
  bf16x8 gv = *(const bf16x8*)(gg + lane * 8);
  bf16x8 bv = *(const bf16x8*)(bb + lane * 8);
  bf16x8 o;
#pragma unroll
  for (int i = 0; i < 8; ++i) o[i] = (bf16)((f[i] - mean) * rs * (float)gv[i] + (float)bv[i]);
  *(bf16x8*)((bf16*)out + base) = o;
}

// ---------------- GEMM: C = A(MxK) @ Bw(N x K, row-stride bstride)^T ----------------
// 128x128 tile, 4 waves, 3-buffer depth-2 COUNTED-vmcnt pipeline (T4):
//   stage tile t+2 while computing tile t; per-iteration tail = vmcnt(4)
//   (wait only tile t+1's 4 loads; tile t+2's loads stay in flight across the
//   barrier) + raw s_barrier. Never vmcnt(0) in steady state -- unlike
//   __syncthreads, which drains the just-issued prefetch every iteration.
// Ledger: b[(t+2)%3] last read at iter t-1, fenced by that iter's tail
// barrier; each wave's vmcnt(4) precedes the barrier so all waves' tile-t+1
// portions are in LDS before any wave reads them. Tail iter t=nt-2 uses
// vmcnt(0) (no t+2 stage); iter nt-1 has no tail sync.
// Epilogues are BARRIER-FREE: final iteration reads b[(nt-1)%3]; epilogue
// restage regions live in b[nt%3] (quiescent: nothing outstanding, not read
// by final MFMA, per-wave private). b16 modes: 4x1152 el = 9216 B <= 16 KiB;
// f32 modes: 4x1024 floats = 16 KiB exactly.
// MODE 0: QKV -> q,k,v head-major [bh][n][64]; q/k fused l2norm*scale+rope
// MODE 1: + X(raw x, probe-switched) + bias -> O0 bf16 (stride DIM)
// MODE 2: fast exact gelu -> O0 bf16 (stride ostride)
// MODE 3: + Xb(bf16, stride DIM) -> Of fp32 (stride DIM)
// MODE 4: + Of(read-back fp32)   -> Of fp32 (stride DIM)
template <int MODE>
__global__ __launch_bounds__(256) void gemm_bt(const bf16* __restrict__ A,
                                               const bf16* __restrict__ Bw,
                                               bf16* __restrict__ O0, bf16* __restrict__ O1,
                                               bf16* __restrict__ O2,
                                               float* __restrict__ Of,
                                               const void* __restrict__ Xraw,
                                               const bf16* __restrict__ Xb,
                                               const bf16* __restrict__ bias,
                                               const unsigned short* __restrict__ probe,
                                               int K, int bstride, int ostride, int gx) {
  __shared__ __align__(16) bf16 smem[3 * 8192];       // 48 KB: three (As,Bs) buffers
  const int tid = threadIdx.x;
  const int wave = tid >> 6, lane = tid & 63;
  const int l15 = lane & 15, quad = lane >> 4;
  // XCD-aware swizzle (8 m-strips per XCD group, n fastest within)
  const int id = blockIdx.x;
  const int per = gx * 8;
  const int tM = ((id / per) * 8 + (id & 7)) * 128;
  const int tN = ((id % per) >> 3) * 128;
  const int wM = (wave >> 1) * 64, wN = (wave & 1) * 64;
  f32x4 acc[4][4];
  const f32x4 z = {0.f, 0.f, 0.f, 0.f};
#pragma unroll
  for (int i = 0; i < 4; ++i)
#pragma unroll
    for (int j = 0; j < 4; ++j) acc[i][j] = z;

  auto stage = [&](int t, int p) {                    // 4 gload_lds per thread
    const int k0 = t * 32;
    bf16* dA = smem + p * 8192;
    bf16* dB = dA + 4096;
#pragma unroll
    for (int tt = 0; tt < 2; ++tt) {
      const int c = tid + tt * 256;                   // 512 16B-chunks per tile
      const int row = c >> 2, cc = (c & 3) * 8;
      gload_lds16(A + (size_t)(tM + row) * K + k0 + cc, &dA[c * 8]);
      gload_lds16(Bw + (size_t)(tN + row) * bstride + k0 + cc, &dB[c * 8]);
    }
  };

  const int nt = K >> 5;                              // >= 16 in all uses
  stage(0, 0);
  stage(1, 1);
  __builtin_amdgcn_sched_barrier(0);
  asm volatile("s_waitcnt vmcnt(4)" ::: "memory");    // tile0 landed (tile1 in flight)
  __builtin_amdgcn_s_barrier();
  __builtin_amdgcn_sched_barrier(0);

  int cur = 0;
  for (int t = 0; t < nt; ++t) {
    if (t + 2 < nt) {
      int nx = cur + 2; if (nx >= 3) nx -= 3;
      stage(t + 2, nx);                               // overwrites buffer read at t-1
    }
    const bf16* As = smem + cur * 8192;
    const bf16* Bs = As + 4096;
    bf16x8 aF[4], bF[4];
#pragma unroll
    for (int i = 0; i < 4; ++i) aF[i] = *(const bf16x8*)&As[(wM + i * 16 + l15) * 32 + quad * 8];
#pragma unroll
    for (int j = 0; j < 4; ++j) bF[j] = *(const bf16x8*)&Bs[(wN + j * 16 + l15) * 32 + quad * 8];
#pragma unroll
    for (int i = 0; i < 4; ++i)
#pragma unroll
      for (int j = 0; j < 4; ++j) acc[i][j] = mfma16(aF[i], bF[j], acc[i][j]);
    if (t < nt - 1) {
      __builtin_amdgcn_sched_barrier(0);
      if (t + 2 < nt) asm volatile("s_waitcnt vmcnt(4)" ::: "memory");  // t+1 landed
      else            asm volatile("s_waitcnt vmcnt(0)" ::: "memory");  // drain tail
      __builtin_amdgcn_s_barrier();
      __builtin_amdgcn_sched_barrier(0);
    }
    ++cur; if (cur == 3) cur = 0;
  }
  // post-loop: cur == nt%3 == the buffer NOT read in the final iteration.
  bf16* eb = smem + cur * 8192;                       // quiescent epilogue buffer

  if constexpr (MODE == 0) {
    // wave's 64-col span is exactly one (q/k/v, head) plane; fused rope for q/k
    bf16* ob = eb + wave * 1152;                      // per-wave 16 x 72 tile
    const int colbase = tN + wN;
    const int which = colbase >> 9;
    const int head = (colbase >> 6) & 7;
    bf16* dst = which == 0 ? O0 : (which == 1 ? O1 : O2);
    const int ch = lane & 7;
    float scv[8], invf[8];
    if (which < 2) {
      const bf16* sc = which ? bias : Xb;             // ksc : qsc
      bf16x8 s8 = *(const bf16x8*)(sc + ch * 8);
#pragma unroll
      for (int u = 0; u < 8; ++u) {
        scv[u] = (float)s8[u] * (which == 0 ? 8.0f : 1.0f);   // fold QK_SCALE into q
        invf[u] = exp2f(-(float)((ch & 3) * 8 + u) * (13.287712379549449f / 32.0f));
      }
    }
#pragma unroll
    for (int i = 0; i < 4; ++i) {
#pragma unroll
      for (int j = 0; j < 4; ++j)
#pragma unroll
        for (int r = 0; r < 4; ++r)
          ob[(quad * 4 + r) * 72 + j * 16 + l15] = (bf16)acc[i][j][r];
#pragma unroll
      for (int t = 0; t < 2; ++t) {
        const int rr = t * 8 + (lane >> 3);
        const int rowg = tM + wM + i * 16 + rr;
        bf16x8 ov = *(const bf16x8*)&ob[rr * 72 + ch * 8];
        float f[8];
#pragma unroll
        for (int u = 0; u < 8; ++u) f[u] = (float)ov[u];
        if (which < 2) {
          float ss = 0.f;
#pragma unroll
          for (int u = 0; u < 8; ++u) ss += f[u] * f[u];
          ss += __shfl_xor(ss, 1); ss += __shfl_xor(ss, 2); ss += __shfl_xor(ss, 4);
          const float rs = 1.0f / fmaxf(sqrtf(ss), 1e-12f);
#pragma unroll
          for (int u = 0; u < 8; ++u) f[u] *= rs * scv[u];
          float pf[8];
#pragma unroll
          for (int u = 0; u < 8; ++u) pf[u] = __shfl_xor(f[u], 4);
          const float pos = (float)(rowg & (SEQ - 1));
#pragma unroll
          for (int u = 0; u < 8; ++u) {
            float sn, cs;
            __sincosf(pos * invf[u], &sn, &cs);
            const float rot = (ch < 4) ? -pf[u] : pf[u];
            f[u] = f[u] * cs + rot * sn;
          }
        }
        bf16x8 o8;
#pragma unroll
        for (int u = 0; u < 8; ++u) o8[u] = (bf16)f[u];
        const int bb = rowg >> 12, n = rowg & (SEQ - 1);
        *(bf16x8*)(dst + ((size_t)(bb * HEADS + head) * SEQ + n) * DH + ch * 8) = o8;
      }
    }
    return;
  }

  if constexpr (MODE == 1 || MODE == 2) {
    // coalesced epilogue via per-wave LDS restage (barrier-free; region in eb)
    bf16* ob = eb + wave * 1152;                      // 16 x 72
    const int ch = lane & 7;
    bf16x8 bias8;
    bool xf32 = false;
    if constexpr (MODE == 1) {
      bias8 = *(const bf16x8*)(bias + tN + wN + ch * 8);
      xf32 = (probe[0] == 0);
    }
#pragma unroll
    for (int i = 0; i < 4; ++i) {
#pragma unroll
      for (int j = 0; j < 4; ++j)
#pragma unroll
        for (int r = 0; r < 4; ++r)
          ob[(quad * 4 + r) * 72 + j * 16 + l15] = (bf16)acc[i][j][r];
#pragma unroll
      for (int t = 0; t < 2; ++t) {
        const int rr = t * 8 + (lane >> 3);
        const int rowg = tM + wM + i * 16 + rr;
        bf16x8 ov = *(const bf16x8*)&ob[rr * 72 + ch * 8];
        bf16x8 o8;
        if constexpr (MODE == 1) {
          const size_t idx = (size_t)rowg * DIM + tN + wN + ch * 8;
          float xr[8];
          if (xf32) {
            const float4* xp = (const float4*)((const float*)Xraw + idx);
            float4 a = xp[0], bq = xp[1];
            xr[0] = a.x; xr[1] = a.y; xr[2] = a.z; xr[3] = a.w;
            xr[4] = bq.x; xr[5] = bq.y; xr[6] = bq.z; xr[7] = bq.w;
          } else {
            bf16x8 xv = *(const bf16x8*)((const bf16*)Xraw + idx);
#pragma unroll
            for (int u = 0; u < 8; ++u) xr[u] = (float)xv[u];
          }
#pragma unroll
          for (int u = 0; u < 8; ++u) o8[u] = (bf16)((float)ov[u] + xr[u] + (float)bias8[u]);
          *(bf16x8*)(O0 + idx) = o8;
        } else {
#pragma unroll
          for (int u = 0; u < 8; ++u) o8[u] = (bf16)fast_gelu((float)ov[u]);
          *(bf16x8*)(O0 + (size_t)rowg * ostride + tN + wN + ch * 8) = o8;
        }
      }
    }
    return;
  }

  if constexpr (MODE == 3 || MODE == 4) {
    // fp32 LDS restage -> float4 stores (barrier-free; 4 waves x 1024 floats
    // = 16 KiB = exactly one buffer)
    float* obf = (float*)eb + wave * 1024;            // 16 x 64 floats
    const int ch = lane & 7;
#pragma unroll
    for (int i = 0; i < 4; ++i) {
#pragma unroll
      for (int j = 0; j < 4; ++j)
#pragma unroll
        for (int r = 0; r < 4; ++r)
          obf[(quad * 4 + r) * 64 + j * 16 + l15] = acc[i][j][r];
#pragma unroll
      for (int t = 0; t < 2; ++t) {
        const int rr = t * 8 + (lane >> 3);
        const int rowg = tM + wM + i * 16 + rr;
        const size_t idx = (size_t)rowg * DIM + tN + wN + ch * 8;
        const float4* rp = (const float4*)&obf[rr * 64 + ch * 8];
        float4 a = rp[0], b = rp[1];
        float f[8] = {a.x, a.y, a.z, a.w, b.x, b.y, b.z, b.w};
        if constexpr (MODE == 3) {
          bf16x8 xv = *(const bf16x8*)(Xb + idx);
#pragma unroll
          for (int u = 0; u < 8; ++u) f[u] += (float)xv[u];
        } else {
          const float4* op = (const float4*)(Of + idx);
          float4 oa = op[0], ob4 = op[1];
          f[0] += oa.x; f[1] += oa.y; f[2] += oa.z; f[3] += oa.w;
          f[4] += ob4.x; f[5] += ob4.y; f[6] += ob4.z; f[7] += ob4.w;
        }
        float4 o0 = {f[0], f[1], f[2], f[3]}, o1 = {f[4], f[5], f[6], f[7]};
        ((float4*)(Of + idx))[0] = o0;
        ((float4*)(Of + idx))[1] = o1;
      }
    }
    return;
  }
}

// ---------------- windowed attention: one block per (b,h,window) ----------------
__global__ __launch_bounds__(256, 3) void attn_kernel(const bf16* __restrict__ q,
                                                      const bf16* __restrict__ k,
                                                      const bf16* __restrict__ v,
                                                      bf16* __restrict__ ao) {
  __shared__ __align__(16) bf16 kv[256 * 72];       // K [tok][72]; later V^T [d][264]
  __shared__ __align__(16) bf16 pbuf[4][16 * 136];  // per-wave half-P / O tile
  const int w = blockIdx.x, h = blockIdx.y, b = blockIdx.z;
  const int tid = threadIdx.x;
  const int wv = tid >> 6, lane = tid & 63;
  const int l15 = lane & 15, quad = lane >> 4;
  const size_t bh = (size_t)b * HEADS + h;
  const bf16* qb = q + bh * SEQ * DH;
  const bf16* kb = k + bh * SEQ * DH;
  const bf16* vb = v + bh * SEQ * DH;
  const int t0 = (w - 1) * WIN;                     // tile token range [t0, t0+256)

#pragma unroll
  for (int it = 0; it < 8; ++it) {
    const int c = it * 256 + tid;
    const int tok = c >> 3, ch = c & 7;
    int gt = t0 + tok; gt = gt < 0 ? 0 : gt;
    *(bf16x8*)&kv[tok * 72 + ch * 8] = *(const bf16x8*)(kb + (size_t)gt * DH + ch * 8);
  }
  bf16x8 aQ[2][2];
#pragma unroll
  for (int qt = 0; qt < 2; ++qt) {
    const int qtok = w * WIN + wv * 32 + qt * 16 + l15;
#pragma unroll
    for (int ks = 0; ks < 2; ++ks)
      aQ[qt][ks] = *(const bf16x8*)(qb + (size_t)qtok * DH + ks * 32 + quad * 8);
  }
  int gtv = t0 + tid; gtv = gtv < 0 ? 0 : gtv;
  bf16x8 vld[8];
#pragma unroll
  for (int dg = 0; dg < 8; ++dg)
    vld[dg] = *(const bf16x8*)(vb + (size_t)gtv * DH + dg * 8);
  __syncthreads();

  bf16x8 aP[2][8];
#pragma unroll
  for (int qt = 0; qt < 2; ++qt) {
    f32x4 sreg[16];
#pragma unroll
    for (int nt = 0; nt < 16; ++nt) {
      f32x4 a = {0.f, 0.f, 0.f, 0.f};
#pragma unroll
      for (int ks = 0; ks < 2; ++ks) {
        bf16x8 bK = *(const bf16x8*)&kv[(nt * 16 + l15) * 72 + ks * 32 + quad * 8];
        a = mfma16(aQ[qt][ks], bK, a);
      }
      sreg[nt] = a;
    }
    const int qlb = wv * 32 + qt * 16 + quad * 4;
    float rinv[4];
#pragma unroll
    for (int r = 0; r < 4; ++r) {
      const int ql = qlb + r;
      float sum = 0.f;
#pragma unroll
      for (int nt = 0; nt < 16; ++nt) {
        const int j = nt * 16 + l15;
        const bool valid = (nt < 8) ? (w > 0) : (ql >= j - WIN);
        const float p = valid ? __expf(sreg[nt][r]) : 0.0f;   // no max-sub: |s|<=8
        sreg[nt][r] = p;
        sum += p;
      }
#pragma unroll
      for (int m = 8; m; m >>= 1) sum += __shfl_xor(sum, m);
      rinv[r] = 1.0f / sum;
    }
#pragma unroll
    for (int half = 0; half < 2; ++half) {
#pragma unroll
      for (int ntw = 0; ntw < 8; ++ntw)
#pragma unroll
        for (int r = 0; r < 4; ++r)
          pbuf[wv][(quad * 4 + r) * 136 + ntw * 16 + l15] =
              (bf16)(sreg[half * 8 + ntw][r] * rinv[r]);
#pragma unroll
      for (int kk = 0; kk < 4; ++kk)
        aP[qt][half * 4 + kk] = *(const bf16x8*)&pbuf[wv][l15 * 136 + kk * 32 + quad * 8];
    }
  }
  __syncthreads();

#pragma unroll
  for (int dg = 0; dg < 8; ++dg)
#pragma unroll
    for (int i = 0; i < 8; ++i)
      kv[(dg * 8 + i) * 264 + tid] = vld[dg][i];
  __syncthreads();

#pragma unroll
  for (int qt = 0; qt < 2; ++qt) {
#pragma unroll
    for (int dt = 0; dt < 4; ++dt) {
      f32x4 o = {0.f, 0.f, 0.f, 0.f};
#pragma unroll
      for (int ks2 = 0; ks2 < 8; ++ks2) {
        bf16x8 bV = *(const bf16x8*)&kv[(dt * 16 + l15) * 264 + ks2 * 32 + quad * 8];
        o = mfma16(aP[qt][ks2], bV, o);
      }
#pragma unroll
      for (int r = 0; r < 4; ++r)
        pbuf[wv][(quad * 4 + r) * 136 + dt * 16 + l15] = (bf16)o[r];
    }
#pragma unroll
    for (int t = 0; t < 2; ++t) {
      const int rr = t * 8 + (lane >> 3), ch = lane & 7;
      bf16x8 ov = *(const bf16x8*)&pbuf[wv][rr * 136 + ch * 8];
      const int tok = w * WIN + wv * 32 + qt * 16 + rr;
      *(bf16x8*)(ao + ((size_t)b * SEQ + tok) * DIM + h * DH + ch * 8) = ov;
    }
  }
}

extern "C" void kernel_launch(void* const* d_in, const int* in_sizes, int n_in,
                              void* d_out, int out_size, void* d_ws, size_t ws_size,
                              hipStream_t stream) {
  (void)in_sizes; (void)n_in; (void)out_size;
  float* out = (float*)d_out;                      // fp32 output per reference dtype
  bf16* cano = (bf16*)d_ws;
  const unsigned short* probe = (const unsigned short*)d_in[2];

  SrcPtrs sp;
  for (int i = 0; i < 12; ++i) sp.p[i] = d_in[i];

  bf16* slot0 = cano + P_EL;             // h -> ao -> hf
  bf16* slot1 = cano + P_EL + R_EL;      // q -> x2
  bf16* slot2 = cano + P_EL + 2 * R_EL;  // k ; later f1
  bf16* slot3 = cano + P_EL + 3 * R_EL;  // v (natural head-major layout)

  const bf16* qsc  = cano + C_SM + 0;
  const bf16* ksc  = cano + C_SM + 64;
  const bf16* bout = cano + C_SM + 128;
  const bf16* l1g  = cano + C_SM + 640;
  const bf16* l1b  = cano + C_SM + 1152;
  const bf16* lfg  = cano + C_SM + 1664;
  const bf16* lfb  = cano + C_SM + 2176;

  ingest_kernel<<<1538, 256, 0, stream>>>(sp, cano);
  ln_kernel<<<TOK / 4, 256, 0, stream>>>(d_in[0], l1g, l1b, slot0, probe, 1);
  gemm_bt<0><<<12 * 256, 256, 0, stream>>>(slot0, cano + C_QKV, slot1, slot2, slot3,
                                           nullptr, nullptr, qsc, ksc, probe,
                                           DIM, DIM, 0, 12);
  attn_kernel<<<dim3(NW, HEADS, BATCH), 256, 0, stream>>>(slot1, slot2, slot3, slot0);
  gemm_bt<1><<<4 * 256, 256, 0, stream>>>(slot0, cano + C_WOUT, slot1, nullptr, nullptr,
                                          nullptr, d_in[0], nullptr, bout, probe,
                                          DIM, DIM, 0, 4);
  ln_kernel<<<TOK / 4, 256, 0, stream>>>(slot1, lfg, lfb, slot0, probe, 0);

  const bool big = ws_size >= (size_t)(P_EL + 6 * R_EL) * 2;
  if (big) {
    bf16* f1 = slot2;                    // spans slot2..slot5 (4R)
    gemm_bt<2><<<16 * 256, 256, 0, stream>>>(slot0, cano + C_WF1, f1, nullptr, nullptr,
                                             nullptr, nullptr, nullptr, nullptr, probe,
                                             DIM, DIM, 2048, 16);
    gemm_bt<3><<<4 * 256, 256, 0, stream>>>(f1, cano + C_WF2, nullptr, nullptr, nullptr,
                                            out, nullptr, slot1, nullptr, probe,
                                            2048, 2048, 0, 4);
  } else {
    bf16* f1h = slot2;                   // TOK x 1024 bf16 = 2R
    for (int half = 0; half < 2; ++half) {
      const bf16* w1h = cano + C_WF1 + (size_t)half * 1024 * DIM;
      const bf16* w2h = cano + C_WF2 + (size_t)half * 1024;
      gemm_bt<2><<<8 * 256, 256, 0, stream>>>(slot0, w1h, f1h, nullptr, nullptr,
                                              nullptr, nullptr, nullptr, nullptr, probe,
                                              DIM, DIM, 1024, 8);
      if (half == 0)
        gemm_bt<3><<<4 * 256, 256, 0, stream>>>(f1h, w2h, nullptr, nullptr, nullptr,
                                                out, nullptr, slot1, nullptr, probe,
                                                1024, 2048, 0, 4);
      else
        gemm_bt<4><<<4 * 256, 256, 0, stream>>>(f1h, w2h, nullptr, nullptr, nullptr,
                                                out, nullptr, nullptr, nullptr, probe,
                                                1024, 2048, 0, 4);
    }
  }
}

// Round 5
// 497.408 us; speedup vs baseline: 1.1577x; 1.0170x over previous
//
#include <hip/hip_runtime.h>
#include <cstdint>
#include <cstddef>

typedef __bf16 bf16;
typedef __bf16 bf16x8 __attribute__((ext_vector_type(8)));
typedef float f32x4 __attribute__((ext_vector_type(4)));

#define DEV static __device__ __forceinline__

constexpr int BATCH = 8;
constexpr int SEQ = 4096;
constexpr int DIM = 512;
constexpr int HEADS = 8;
constexpr int DH = 64;
constexpr int WIN = 128;
constexpr int NW = SEQ / WIN;        // 32
constexpr int TOK = BATCH * SEQ;     // 32768
constexpr float EPS = 1e-5f;

// canonical bf16 weights in workspace (element offsets)
constexpr size_t R_EL   = (size_t)TOK * DIM;            // 16,777,216
constexpr size_t C_QKV  = 0;                             // 786432
constexpr size_t C_WOUT = 786432;                        // 262144
constexpr size_t C_WF1  = 1048576;                       // 1048576
constexpr size_t C_WF2  = 2097152;                       // 1048576
constexpr size_t C_SM   = 3145728;                       // 2688 smalls
// smalls: qsc 0, ksc 64, bout 128, l1g 640, l1b 1152, lfg 1664, lfb 2176
constexpr size_t P_EL   = 3148416;                       // slot base (%8==0)

DEV void gload_lds16(const void* g, void* l) {
  __builtin_amdgcn_global_load_lds((__attribute__((address_space(1))) void*)g,
                                   (__attribute__((address_space(3))) void*)l,
                                   16, 0, 0);
}

DEV f32x4 mfma16(bf16x8 a, bf16x8 b, f32x4 c) {
  return __builtin_amdgcn_mfma_f32_16x16x32_bf16(a, b, c, 0, 0, 0);
}

// Branchless exact-GELU via Abramowitz-Stegun 7.1.26 erf approximation.
// |erf error| <= 1.5e-7 (far below bf16 output rounding). ~16 cheap VALU ops,
// no divergence -- vs library erff's two-path implementation.
DEV float fast_gelu(float v) {
  const float z = fabsf(v) * 0.7071067811865476f;
  const float t = __builtin_amdgcn_rcpf(1.0f + 0.3275911f * z);
  const float p = t * (0.254829592f +
                  t * (-0.284496736f +
                  t * (1.421413741f +
                  t * (-1.453152027f +
                  t * 1.061405429f))));
  const float e = __expf(-z * z);
  const float erfa = 1.0f - p * e;               // erf(|v|/sqrt2)
  const float cdf = 0.5f + copysignf(0.5f * erfa, v);
  return v * cdf;
}

// ---------------- ingest: dtype-probe + convert weight inputs to bf16 ----------
struct SrcPtrs { const void* p[12]; };

DEV void copy8(const void* src, long si, bf16* dst, bool f32) {
  if (f32) {
    const float4* s = (const float4*)((const float*)src + si);
    float4 a = s[0], b = s[1];
    bf16x8 o;
    o[0] = (bf16)a.x; o[1] = (bf16)a.y; o[2] = (bf16)a.z; o[3] = (bf16)a.w;
    o[4] = (bf16)b.x; o[5] = (bf16)b.y; o[6] = (bf16)b.z; o[7] = (bf16)b.w;
    *(bf16x8*)dst = o;
  } else {
    *(bf16x8*)dst = *(const bf16x8*)((const bf16*)src + si);
  }
}

__global__ __launch_bounds__(256) void ingest_kernel(SrcPtrs sp, bf16* cano) {
  const bool f32 = (((const unsigned short*)sp.p[2])[0] == 0);
  const long e = (long)threadIdx.x * 8;
  int b = blockIdx.x;
  if (b < 384)  { long o = (long)b * 2048 + e; copy8(sp.p[1], o, cano + C_QKV + o, f32); return; }
  b -= 384;
  if (b < 128)  { long o = (long)b * 2048 + e; copy8(sp.p[4], o, cano + C_WOUT + o, f32); return; }
  b -= 128;
  if (b < 512)  { long o = (long)b * 2048 + e; copy8(sp.p[10], o, cano + C_WF1 + o, f32); return; }
  b -= 512;
  if (b < 512)  { long o = (long)b * 2048 + e; copy8(sp.p[11], o, cano + C_WF2 + o, f32); return; }
  b -= 512;
  const long o = (long)b * 2048 + e;
  if (o >= 2688) return;
  const void* src; long si;
  if      (o < 64)   { src = sp.p[2]; si = o; }
  else if (o < 128)  { src = sp.p[3]; si = o - 64; }
  else if (o < 640)  { src = sp.p[5]; si = o - 128; }
  else if (o < 1152) { src = sp.p[6]; si = o - 640; }
  else if (o < 1664) { src = sp.p[7]; si = o - 1152; }
  else if (o < 2176) { src = sp.p[8]; si = o - 1664; }
  else               { src = sp.p[9]; si = o - 2176; }
  copy8(src, si, cano + C_SM + o, f32);
}

// ---------------- LayerNorm: one wave per 512-dim token ----------------
__global__ __launch_bounds__(256) void ln_kernel(const void* __restrict__ in,
                                                 const bf16* __restrict__ gg,
                                                 const bf16* __restrict__ bb,
                                                 bf16* __restrict__ out,
                                                 const unsigned short* __restrict__ probe,
                                                 int raw) {
  const int wave = threadIdx.x >> 6, lane = threadIdx.x & 63;
  const int row = blockIdx.x * 4 + wave;
  const size_t base = (size_t)row * DIM + lane * 8;
  float f[8];
  if (raw && probe[0] == 0) {
    const float4* p = (const float4*)((const float*)in + base);
    float4 a = p[0], bq = p[1];
    f[0] = a.x; f[1] = a.y; f[2] = a.z; f[3] = a.w;
    f[4] = bq.x; f[5] = bq.y; f[6] = bq.z; f[7] = bq.w;
  } else {
    bf16x8 v = *(const bf16x8*)((const bf16*)in + base);
#pragma unroll
    for (int i = 0; i < 8; ++i) f[i] = (float)v[i];
  }
  float s = 0.f, sq = 0.f;
#pragma unroll
  for (int i = 0; i < 8; ++i) { s += f[i]; sq += f[i] * f[i]; }
#pragma unroll
  for (int m = 32; m; m >>= 1) { s += __shfl_xor(s, m); sq += __shfl_xor(sq, m); }
  const float mean = s * (1.0f / DIM);
  const float var = fmaxf(sq * (1.0f / DIM) - mean * mean, 0.0f);
  const float rs = rsqrtf(var + EPS);
  bf16x8 gv = *(const bf16x8*)(gg + lane * 8);
  bf16x8 bv = *(const bf16x8*)(bb + lane * 8);
  bf16x8 o;
#pragma unroll
  for (int i = 0; i < 8; ++i) o[i] = (bf16)((f[i] - mean) * rs * (float)gv[i] + (float)bv[i]);
  *(bf16x8*)((bf16*)out + base) = o;
}

// ---------------- GEMM: C = A(MxK) @ Bw(N x K, row-stride bstride)^T ----------------
// 256x128 tile, 8 waves (4M x 2N, per-wave 64x64), 3-buffer depth-2
// COUNTED-vmcnt pipeline (T4): stage tile t+2 while computing tile t;
// per-iteration tail = vmcnt(3) (wait only tile t+1's 3 loads/thread; tile
// t+2's stay in flight across the barrier) + raw s_barrier. Never vmcnt(0)
// in steady state. Stage = 3 uniform loads/thread (2 A-chunks + 1 B-chunk,
// 1536 chunks / 512 threads). Buffer = A 256x32 + B 128x32 = 24 KiB; x3 =
// 72 KiB dynamic LDS -> 2 blocks/CU x 8 waves = 16 waves/CU.
// Ledger: b[(t+2)%3] last read at iter t-1, fenced by that iter's tail
// barrier; per-wave vmcnt(3) precedes the barrier so all waves' tile-t+1
// loads are in LDS before any wave reads them. Tail iter t=nt-2 uses
// vmcnt(0) (drains everything); iter nt-1 has no tail sync.
// Epilogues BARRIER-FREE: final iter reads b[(nt-1)%3]; buffers q0=nt%3 and
// q1=(nt+1)%3 are quiescent. b16 restage: 8 waves x 1152 el = 18 KiB <= q0.
// f32 restage: waves 0-5 in q0 (6x4 KiB = 24 KiB exactly), waves 6-7 in q1.
// MODE 0: QKV -> q,k,v head-major [bh][n][64]; q/k fused l2norm*scale+rope
// MODE 1: + X(raw x, probe-switched) + bias -> O0 bf16 (stride DIM)
// MODE 2: fast exact gelu -> O0 bf16 (stride ostride)
// MODE 3: + Xb(bf16, stride DIM) -> Of fp32 (stride DIM)
// MODE 4: + Of(read-back fp32)   -> Of fp32 (stride DIM)
template <int MODE>
__global__ __launch_bounds__(512) void gemm_bt(const bf16* __restrict__ A,
                                               const bf16* __restrict__ Bw,
                                               bf16* __restrict__ O0, bf16* __restrict__ O1,
                                               bf16* __restrict__ O2,
                                               float* __restrict__ Of,
                                               const void* __restrict__ Xraw,
                                               const bf16* __restrict__ Xb,
                                               const bf16* __restrict__ bias,
                                               const unsigned short* __restrict__ probe,
                                               int K, int bstride, int ostride, int gx) {
  extern __shared__ __align__(16) bf16 smem[];        // 3 * 12288 elems = 72 KiB
  const int tid = threadIdx.x;
  const int wid = tid >> 6, lane = tid & 63;
  const int l15 = lane & 15, quad = lane >> 4;
  // XCD-aware swizzle (8 m-strips per XCD group, n fastest within)
  const int id = blockIdx.x;
  const int per = gx * 8;
  const int tM = ((id / per) * 8 + (id & 7)) * 256;
  const int tN = ((id % per) >> 3) * 128;
  const int wM = (wid >> 1) * 64, wN = (wid & 1) * 64;
  f32x4 acc[4][4];
  const f32x4 z = {0.f, 0.f, 0.f, 0.f};
#pragma unroll
  for (int i = 0; i < 4; ++i)
#pragma unroll
    for (int j = 0; j < 4; ++j) acc[i][j] = z;

  auto stage = [&](int t, int p) {                    // 3 gload_lds per thread
    const int k0 = t * 32;
    bf16* dA = smem + p * 12288;
    bf16* dB = dA + 8192;
    {                                                 // A: 1024 chunks (256x32)
      const int c = tid, row = c >> 2, cc = (c & 3) * 8;
      gload_lds16(A + (size_t)(tM + row) * K + k0 + cc, &dA[c * 8]);
    }
    {
      const int c = tid + 512, row = c >> 2, cc = (c & 3) * 8;
      gload_lds16(A + (size_t)(tM + row) * K + k0 + cc, &dA[c * 8]);
    }
    {                                                 // B: 512 chunks (128x32)
      const int c = tid, row = c >> 2, cc = (c & 3) * 8;
      gload_lds16(Bw + (size_t)(tN + row) * bstride + k0 + cc, &dB[c * 8]);
    }
  };

  const int nt = K >> 5;                              // >= 16 in all uses
  stage(0, 0);
  stage(1, 1);
  __builtin_amdgcn_sched_barrier(0);
  asm volatile("s_waitcnt vmcnt(3)" ::: "memory");    // tile0 landed (tile1 in flight)
  __builtin_amdgcn_s_barrier();
  __builtin_amdgcn_sched_barrier(0);

  int cur = 0;
  for (int t = 0; t < nt; ++t) {
    if (t + 2 < nt) {
      int nx = cur + 2; if (nx >= 3) nx -= 3;
      stage(t + 2, nx);                               // overwrites buffer read at t-1
    }
    const bf16* As = smem + cur * 12288;
    const bf16* Bs = As + 8192;
    bf16x8 aF[4], bF[4];
#pragma unroll
    for (int i = 0; i < 4; ++i) aF[i] = *(const bf16x8*)&As[(wM + i * 16 + l15) * 32 + quad * 8];
#pragma unroll
    for (int j = 0; j < 4; ++j) bF[j] = *(const bf16x8*)&Bs[(wN + j * 16 + l15) * 32 + quad * 8];
#pragma unroll
    for (int i = 0; i < 4; ++i)
#pragma unroll
      for (int j = 0; j < 4; ++j) acc[i][j] = mfma16(aF[i], bF[j], acc[i][j]);
    if (t < nt - 1) {
      __builtin_amdgcn_sched_barrier(0);
      if (t + 2 < nt) asm volatile("s_waitcnt vmcnt(3)" ::: "memory");  // t+1 landed
      else            asm volatile("s_waitcnt vmcnt(0)" ::: "memory");  // drain tail
      __builtin_amdgcn_s_barrier();
      __builtin_amdgcn_sched_barrier(0);
    }
    ++cur; if (cur == 3) cur = 0;
  }
  // quiescent epilogue buffers (see header comment)
  const int q0 = nt % 3;
  int q1 = q0 + 1; if (q1 == 3) q1 = 0;
  bf16* eb = smem + q0 * 12288;

  if constexpr (MODE == 0) {
    // wave's 64-col span is exactly one (q/k/v, head) plane; fused rope for q/k
    bf16* ob = eb + wid * 1152;                       // per-wave 16 x 72 tile
    const int colbase = tN + wN;
    const int which = colbase >> 9;
    const int head = (colbase >> 6) & 7;
    bf16* dst = which == 0 ? O0 : (which == 1 ? O1 : O2);
    const int ch = lane & 7;
    float scv[8], invf[8];
    if (which < 2) {
      const bf16* sc = which ? bias : Xb;             // ksc : qsc
      bf16x8 s8 = *(const bf16x8*)(sc + ch * 8);
#pragma unroll
      for (int u = 0; u < 8; ++u) {
        scv[u] = (float)s8[u] * (which == 0 ? 8.0f : 1.0f);   // fold QK_SCALE into q
        invf[u] = exp2f(-(float)((ch & 3) * 8 + u) * (13.287712379549449f / 32.0f));
      }
    }
#pragma unroll
    for (int i = 0; i < 4; ++i) {
#pragma unroll
      for (int j = 0; j < 4; ++j)
#pragma unroll
        for (int r = 0; r < 4; ++r)
          ob[(quad * 4 + r) * 72 + j * 16 + l15] = (bf16)acc[i][j][r];
#pragma unroll
      for (int t = 0; t < 2; ++t) {
        const int rr = t * 8 + (lane >> 3);
        const int rowg = tM + wM + i * 16 + rr;
        bf16x8 ov = *(const bf16x8*)&ob[rr * 72 + ch * 8];
        float f[8];
#pragma unroll
        for (int u = 0; u < 8; ++u) f[u] = (float)ov[u];
        if (which < 2) {
          float ss = 0.f;
#pragma unroll
          for (int u = 0; u < 8; ++u) ss += f[u] * f[u];
          ss += __shfl_xor(ss, 1); ss += __shfl_xor(ss, 2); ss += __shfl_xor(ss, 4);
          const float rs = 1.0f / fmaxf(sqrtf(ss), 1e-12f);
#pragma unroll
          for (int u = 0; u < 8; ++u) f[u] *= rs * scv[u];
          float pf[8];
#pragma unroll
          for (int u = 0; u < 8; ++u) pf[u] = __shfl_xor(f[u], 4);
          const float pos = (float)(rowg & (SEQ - 1));
#pragma unroll
          for (int u = 0; u < 8; ++u) {
            float sn, cs;
            __sincosf(pos * invf[u], &sn, &cs);
            const float rot = (ch < 4) ? -pf[u] : pf[u];
            f[u] = f[u] * cs + rot * sn;
          }
        }
        bf16x8 o8;
#pragma unroll
        for (int u = 0; u < 8; ++u) o8[u] = (bf16)f[u];
        const int bb = rowg >> 12, n = rowg & (SEQ - 1);
        *(bf16x8*)(dst + ((size_t)(bb * HEADS + head) * SEQ + n) * DH + ch * 8) = o8;
      }
    }
    return;
  }

  if constexpr (MODE == 1 || MODE == 2) {
    // coalesced epilogue via per-wave LDS restage (barrier-free; region in q0)
    bf16* ob = eb + wid * 1152;                       // 16 x 72
    const int ch = lane & 7;
    bf16x8 bias8;
    bool xf32 = false;
    if constexpr (MODE == 1) {
      bias8 = *(const bf16x8*)(bias + tN + wN + ch * 8);
      xf32 = (probe[0] == 0);
    }
#pragma unroll
    for (int i = 0; i < 4; ++i) {
#pragma unroll
      for (int j = 0; j < 4; ++j)
#pragma unroll
        for (int r = 0; r < 4; ++r)
          ob[(quad * 4 + r) * 72 + j * 16 + l15] = (bf16)acc[i][j][r];
#pragma unroll
      for (int t = 0; t < 2; ++t) {
        const int rr = t * 8 + (lane >> 3);
        const int rowg = tM + wM + i * 16 + rr;
        bf16x8 ov = *(const bf16x8*)&ob[rr * 72 + ch * 8];
        bf16x8 o8;
        if constexpr (MODE == 1) {
          const size_t idx = (size_t)rowg * DIM + tN + wN + ch * 8;
          float xr[8];
          if (xf32) {
            const float4* xp = (const float4*)((const float*)Xraw + idx);
            float4 a = xp[0], bq = xp[1];
            xr[0] = a.x; xr[1] = a.y; xr[2] = a.z; xr[3] = a.w;
            xr[4] = bq.x; xr[5] = bq.y; xr[6] = bq.z; xr[7] = bq.w;
          } else {
            bf16x8 xv = *(const bf16x8*)((const bf16*)Xraw + idx);
#pragma unroll
            for (int u = 0; u < 8; ++u) xr[u] = (float)xv[u];
          }
#pragma unroll
          for (int u = 0; u < 8; ++u) o8[u] = (bf16)((float)ov[u] + xr[u] + (float)bias8[u]);
          *(bf16x8*)(O0 + idx) = o8;
        } else {
#pragma unroll
          for (int u = 0; u < 8; ++u) o8[u] = (bf16)fast_gelu((float)ov[u]);
          *(bf16x8*)(O0 + (size_t)rowg * ostride + tN + wN + ch * 8) = o8;
        }
      }
    }
    return;
  }

  if constexpr (MODE == 3 || MODE == 4) {
    // fp32 LDS restage -> float4 stores (barrier-free; waves 0-5 in q0,
    // waves 6-7 in q1; per-wave 16 x 64 floats = 4 KiB)
    float* obf = (wid < 6)
        ? (float*)(smem + q0 * 12288) + wid * 1024
        : (float*)(smem + q1 * 12288) + (wid - 6) * 1024;
    const int ch = lane & 7;
#pragma unroll
    for (int i = 0; i < 4; ++i) {
#pragma unroll
      for (int j = 0; j < 4; ++j)
#pragma unroll
        for (int r = 0; r < 4; ++r)
          obf[(quad * 4 + r) * 64 + j * 16 + l15] = acc[i][j][r];
#pragma unroll
      for (int t = 0; t < 2; ++t) {
        const int rr = t * 8 + (lane >> 3);
        const int rowg = tM + wM + i * 16 + rr;
        const size_t idx = (size_t)rowg * DIM + tN + wN + ch * 8;
        const float4* rp = (const float4*)&obf[rr * 64 + ch * 8];
        float4 a = rp[0], b = rp[1];
        float f[8] = {a.x, a.y, a.z, a.w, b.x, b.y, b.z, b.w};
        if constexpr (MODE == 3) {
          bf16x8 xv = *(const bf16x8*)(Xb + idx);
#pragma unroll
          for (int u = 0; u < 8; ++u) f[u] += (float)xv[u];
        } else {
          const float4* op = (const float4*)(Of + idx);
          float4 oa = op[0], ob4 = op[1];
          f[0] += oa.x; f[1] += oa.y; f[2] += oa.z; f[3] += oa.w;
          f[4] += ob4.x; f[5] += ob4.y; f[6] += ob4.z; f[7] += ob4.w;
        }
        float4 o0 = {f[0], f[1], f[2], f[3]}, o1 = {f[4], f[5], f[6], f[7]};
        ((float4*)(Of + idx))[0] = o0;
        ((float4*)(Of + idx))[1] = o1;
      }
    }
    return;
  }
}

// ---------------- windowed attention: one block per (b,h,window) ----------------
__global__ __launch_bounds__(256, 3) void attn_kernel(const bf16* __restrict__ q,
                                                      const bf16* __restrict__ k,
                                                      const bf16* __restrict__ v,
                                                      bf16* __restrict__ ao) {
  __shared__ __align__(16) bf16 kv[256 * 72];       // K [tok][72]; later V^T [d][264]
  __shared__ __align__(16) bf16 pbuf[4][16 * 136];  // per-wave half-P / O tile
  const int w = blockIdx.x, h = blockIdx.y, b = blockIdx.z;
  const int tid = threadIdx.x;
  const int wv = tid >> 6, lane = tid & 63;
  const int l15 = lane & 15, quad = lane >> 4;
  const size_t bh = (size_t)b * HEADS + h;
  const bf16* qb = q + bh * SEQ * DH;
  const bf16* kb = k + bh * SEQ * DH;
  const bf16* vb = v + bh * SEQ * DH;
  const int t0 = (w - 1) * WIN;                     // tile token range [t0, t0+256)

#pragma unroll
  for (int it = 0; it < 8; ++it) {
    const int c = it * 256 + tid;
    const int tok = c >> 3, ch = c & 7;
    int gt = t0 + tok; gt = gt < 0 ? 0 : gt;
    *(bf16x8*)&kv[tok * 72 + ch * 8] = *(const bf16x8*)(kb + (size_t)gt * DH + ch * 8);
  }
  bf16x8 aQ[2][2];
#pragma unroll
  for (int qt = 0; qt < 2; ++qt) {
    const int qtok = w * WIN + wv * 32 + qt * 16 + l15;
#pragma unroll
    for (int ks = 0; ks < 2; ++ks)
      aQ[qt][ks] = *(const bf16x8*)(qb + (size_t)qtok * DH + ks * 32 + quad * 8);
  }
  int gtv = t0 + tid; gtv = gtv < 0 ? 0 : gtv;
  bf16x8 vld[8];
#pragma unroll
  for (int dg = 0; dg < 8; ++dg)
    vld[dg] = *(const bf16x8*)(vb + (size_t)gtv * DH + dg * 8);
  __syncthreads();

  bf16x8 aP[2][8];
#pragma unroll
  for (int qt = 0; qt < 2; ++qt) {
    f32x4 sreg[16];
#pragma unroll
    for (int nt = 0; nt < 16; ++nt) {
      f32x4 a = {0.f, 0.f, 0.f, 0.f};
#pragma unroll
      for (int ks = 0; ks < 2; ++ks) {
        bf16x8 bK = *(const bf16x8*)&kv[(nt * 16 + l15) * 72 + ks * 32 + quad * 8];
        a = mfma16(aQ[qt][ks], bK, a);
      }
      sreg[nt] = a;
    }
    const int qlb = wv * 32 + qt * 16 + quad * 4;
    float rinv[4];
#pragma unroll
    for (int r = 0; r < 4; ++r) {
      const int ql = qlb + r;
      float sum = 0.f;
#pragma unroll
      for (int nt = 0; nt < 16; ++nt) {
        const int j = nt * 16 + l15;
        const bool valid = (nt < 8) ? (w > 0) : (ql >= j - WIN);
        const float p = valid ? __expf(sreg[nt][r]) : 0.0f;   // no max-sub: |s|<=8
        sreg[nt][r] = p;
        sum += p;
      }
#pragma unroll
      for (int m = 8; m; m >>= 1) sum += __shfl_xor(sum, m);
      rinv[r] = 1.0f / sum;
    }
#pragma unroll
    for (int half = 0; half < 2; ++half) {
#pragma unroll
      for (int ntw = 0; ntw < 8; ++ntw)
#pragma unroll
        for (int r = 0; r < 4; ++r)
          pbuf[wv][(quad * 4 + r) * 136 + ntw * 16 + l15] =
              (bf16)(sreg[half * 8 + ntw][r] * rinv[r]);
#pragma unroll
      for (int kk = 0; kk < 4; ++kk)
        aP[qt][half * 4 + kk] = *(const bf16x8*)&pbuf[wv][l15 * 136 + kk * 32 + quad * 8];
    }
  }
  __syncthreads();

#pragma unroll
  for (int dg = 0; dg < 8; ++dg)
#pragma unroll
    for (int i = 0; i < 8; ++i)
      kv[(dg * 8 + i) * 264 + tid] = vld[dg][i];
  __syncthreads();

#pragma unroll
  for (int qt = 0; qt < 2; ++qt) {
#pragma unroll
    for (int dt = 0; dt < 4; ++dt) {
      f32x4 o = {0.f, 0.f, 0.f, 0.f};
#pragma unroll
      for (int ks2 = 0; ks2 < 8; ++ks2) {
        bf16x8 bV = *(const bf16x8*)&kv[(dt * 16 + l15) * 264 + ks2 * 32 + quad * 8];
        o = mfma16(aP[qt][ks2], bV, o);
      }
#pragma unroll
      for (int r = 0; r < 4; ++r)
        pbuf[wv][(quad * 4 + r) * 136 + dt * 16 + l15] = (bf16)o[r];
    }
#pragma unroll
    for (int t = 0; t < 2; ++t) {
      const int rr = t * 8 + (lane >> 3), ch = lane & 7;
      bf16x8 ov = *(const bf16x8*)&pbuf[wv][rr * 136 + ch * 8];
      const int tok = w * WIN + wv * 32 + qt * 16 + rr;
      *(bf16x8*)(ao + ((size_t)b * SEQ + tok) * DIM + h * DH + ch * 8) = ov;
    }
  }
}

extern "C" void kernel_launch(void* const* d_in, const int* in_sizes, int n_in,
                              void* d_out, int out_size, void* d_ws, size_t ws_size,
                              hipStream_t stream) {
  (void)in_sizes; (void)n_in; (void)out_size;
  float* out = (float*)d_out;                      // fp32 output per reference dtype
  bf16* cano = (bf16*)d_ws;
  const unsigned short* probe = (const unsigned short*)d_in[2];

  SrcPtrs sp;
  for (int i = 0; i < 12; ++i) sp.p[i] = d_in[i];

  bf16* slot0 = cano + P_EL;             // h -> ao -> hf
  bf16* slot1 = cano + P_EL + R_EL;      // q -> x2
  bf16* slot2 = cano + P_EL + 2 * R_EL;  // k ; later f1
  bf16* slot3 = cano + P_EL + 3 * R_EL;  // v (natural head-major layout)

  const bf16* qsc  = cano + C_SM + 0;
  const bf16* ksc  = cano + C_SM + 64;
  const bf16* bout = cano + C_SM + 128;
  const bf16* l1g  = cano + C_SM + 640;
  const bf16* l1b  = cano + C_SM + 1152;
  const bf16* lfg  = cano + C_SM + 1664;
  const bf16* lfb  = cano + C_SM + 2176;

  constexpr int LDSB = 3 * 12288 * 2;    // 73728 B dynamic LDS for gemm_bt
  static bool attr_done = false;
  if (!attr_done) {
    hipFuncSetAttribute((const void*)gemm_bt<0>, hipFuncAttributeMaxDynamicSharedMemorySize, LDSB);
    hipFuncSetAttribute((const void*)gemm_bt<1>, hipFuncAttributeMaxDynamicSharedMemorySize, LDSB);
    hipFuncSetAttribute((const void*)gemm_bt<2>, hipFuncAttributeMaxDynamicSharedMemorySize, LDSB);
    hipFuncSetAttribute((const void*)gemm_bt<3>, hipFuncAttributeMaxDynamicSharedMemorySize, LDSB);
    hipFuncSetAttribute((const void*)gemm_bt<4>, hipFuncAttributeMaxDynamicSharedMemorySize, LDSB);
    attr_done = true;
  }

  ingest_kernel<<<1538, 256, 0, stream>>>(sp, cano);
  ln_kernel<<<TOK / 4, 256, 0, stream>>>(d_in[0], l1g, l1b, slot0, probe, 1);
  gemm_bt<0><<<16 * 96, 512, LDSB, stream>>>(slot0, cano + C_QKV, slot1, slot2, slot3,
                                             nullptr, nullptr, qsc, ksc, probe,
                                             DIM, DIM, 0, 12);
  attn_kernel<<<dim3(NW, HEADS, BATCH), 256, 0, stream>>>(slot1, slot2, slot3, slot0);
  gemm_bt<1><<<16 * 32, 512, LDSB, stream>>>(slot0, cano + C_WOUT, slot1, nullptr, nullptr,
                                             nullptr, d_in[0], nullptr, bout, probe,
                                             DIM, DIM, 0, 4);
  ln_kernel<<<TOK / 4, 256, 0, stream>>>(slot1, lfg, lfb, slot0, probe, 0);

  const bool big = ws_size >= (size_t)(P_EL + 6 * R_EL) * 2;
  if (big) {
    bf16* f1 = slot2;                    // spans slot2..slot5 (4R)
    gemm_bt<2><<<16 * 128, 512, LDSB, stream>>>(slot0, cano + C_WF1, f1, nullptr, nullptr,
                                                nullptr, nullptr, nullptr, nullptr, probe,
                                                DIM, DIM, 2048, 16);
    gemm_bt<3><<<16 * 32, 512, LDSB, stream>>>(f1, cano + C_WF2, nullptr, nullptr, nullptr,
                                               out, nullptr, slot1, nullptr, probe,
                                               2048, 2048, 0, 4);
  } else {
    bf16* f1h = slot2;                   // TOK x 1024 bf16 = 2R
    for (int half = 0; half < 2; ++half) {
      const bf16* w1h = cano + C_WF1 + (size_t)half * 1024 * DIM;
      const bf16* w2h = cano + C_WF2 + (size_t)half * 1024;
      gemm_bt<2><<<16 * 64, 512, LDSB, stream>>>(slot0, w1h, f1h, nullptr, nullptr,
                                                 nullptr, nullptr, nullptr, nullptr, probe,
                                                 DIM, DIM, 1024, 8);
      if (half == 0)
        gemm_bt<3><<<16 * 32, 512, LDSB, stream>>>(f1h, w2h, nullptr, nullptr, nullptr,
                                                   out, nullptr, slot1, nullptr, probe,
                                                   1024, 2048, 0, 4);
      else
        gemm_bt<4><<<16 * 32, 512, LDSB, stream>>>(f1h, w2h, nullptr, nullptr, nullptr,
                                                   out, nullptr, nullptr, nullptr, probe,
                                                   1024, 2048, 0, 4);
    }
  }
}

// Round 6
// 479.117 us; speedup vs baseline: 1.2019x; 1.0382x over previous
//
#include <hip/hip_runtime.h>
#include <cstdint>
#include <cstddef>

typedef __bf16 bf16;
typedef __bf16 bf16x8 __attribute__((ext_vector_type(8)));
typedef float f32x4 __attribute__((ext_vector_type(4)));

#define DEV static __device__ __forceinline__

constexpr int BATCH = 8;
constexpr int SEQ = 4096;
constexpr int DIM = 512;
constexpr int HEADS = 8;
constexpr int DH = 64;
constexpr int WIN = 128;
constexpr int NW = SEQ / WIN;        // 32
constexpr int TOK = BATCH * SEQ;     // 32768
constexpr float EPS = 1e-5f;

// canonical bf16 weights in workspace (element offsets)
constexpr size_t R_EL   = (size_t)TOK * DIM;            // 16,777,216
constexpr size_t C_QKV  = 0;                             // 786432
constexpr size_t C_WOUT = 786432;                        // 262144
constexpr size_t C_WF1  = 1048576;                       // 1048576
constexpr size_t C_WF2  = 2097152;                       // 1048576
constexpr size_t C_SM   = 3145728;                       // 2688 smalls
// smalls: qsc 0, ksc 64, bout 128, l1g 640, l1b 1152, lfg 1664, lfb 2176
constexpr size_t P_EL   = 3148416;                       // slot base (%8==0)

DEV void gload_lds16(const void* g, void* l) {
  __builtin_amdgcn_global_load_lds((__attribute__((address_space(1))) void*)g,
                                   (__attribute__((address_space(3))) void*)l,
                                   16, 0, 0);
}

DEV f32x4 mfma16(bf16x8 a, bf16x8 b, f32x4 c) {
  return __builtin_amdgcn_mfma_f32_16x16x32_bf16(a, b, c, 0, 0, 0);
}

// Branchless exact-GELU via Abramowitz-Stegun 7.1.26 erf approximation.
// |erf error| <= 1.5e-7 (far below bf16 output rounding). ~16 cheap VALU ops,
// no divergence -- vs library erff's two-path implementation.
DEV float fast_gelu(float v) {
  const float z = fabsf(v) * 0.7071067811865476f;
  const float t = __builtin_amdgcn_rcpf(1.0f + 0.3275911f * z);
  const float p = t * (0.254829592f +
                  t * (-0.284496736f +
                  t * (1.421413741f +
                  t * (-1.453152027f +
                  t * 1.061405429f))));
  const float e = __expf(-z * z);
  const float erfa = 1.0f - p * e;               // erf(|v|/sqrt2)
  const float cdf = 0.5f + copysignf(0.5f * erfa, v);
  return v * cdf;
}

// ---------------- ingest: dtype-probe + convert weight inputs to bf16 ----------
struct SrcPtrs { const void* p[12]; };

DEV void copy8(const void* src, long si, bf16* dst, bool f32) {
  if (f32) {
    const float4* s = (const float4*)((const float*)src + si);
    float4 a = s[0], b = s[1];
    bf16x8 o;
    o[0] = (bf16)a.x; o[1] = (bf16)a.y; o[2] = (bf16)a.z; o[3] = (bf16)a.w;
    o[4] = (bf16)b.x; o[5] = (bf16)b.y; o[6] = (bf16)b.z; o[7] = (bf16)b.w;
    *(bf16x8*)dst = o;
  } else {
    *(bf16x8*)dst = *(const bf16x8*)((const bf16*)src + si);
  }
}

__global__ __launch_bounds__(256) void ingest_kernel(SrcPtrs sp, bf16* cano) {
  const bool f32 = (((const unsigned short*)sp.p[2])[0] == 0);
  const long e = (long)threadIdx.x * 8;
  int b = blockIdx.x;
  if (b < 384)  { long o = (long)b * 2048 + e; copy8(sp.p[1], o, cano + C_QKV + o, f32); return; }
  b -= 384;
  if (b < 128)  { long o = (long)b * 2048 + e; copy8(sp.p[4], o, cano + C_WOUT + o, f32); return; }
  b -= 128;
  if (b < 512)  { long o = (long)b * 2048 + e; copy8(sp.p[10], o, cano + C_WF1 + o, f32); return; }
  b -= 512;
  if (b < 512)  { long o = (long)b * 2048 + e; copy8(sp.p[11], o, cano + C_WF2 + o, f32); return; }
  b -= 512;
  const long o = (long)b * 2048 + e;
  if (o >= 2688) return;
  const void* src; long si;
  if      (o < 64)   { src = sp.p[2]; si = o; }
  else if (o < 128)  { src = sp.p[3]; si = o - 64; }
  else if (o < 640)  { src = sp.p[5]; si = o - 128; }
  else if (o < 1152) { src = sp.p[6]; si = o - 640; }
  else if (o < 1664) { src = sp.p[7]; si = o - 1152; }
  else if (o < 2176) { src = sp.p[8]; si = o - 1664; }
  else               { src = sp.p[9]; si = o - 2176; }
  copy8(src, si, cano + C_SM + o, f32);
}

// ---------------- LayerNorm: one wave per 512-dim token ----------------
__global__ __launch_bounds__(256) void ln_kernel(const void* __restrict__ in,
                                                 const bf16* __restrict__ gg,
                                                 const bf16* __restrict__ bb,
                                                 bf16* __restrict__ out,
                                                 const unsigned short* __restrict__ probe,
                                                 int raw) {
  const int wave = threadIdx.x >> 6, lane = threadIdx.x & 63;
  const int row = blockIdx.x * 4 + wave;
  const size_t base = (size_t)row * DIM + lane * 8;
  float f[8];
  if (raw && probe[0] == 0) {
    const float4* p = (const float4*)((const float*)in + base);
    float4 a = p[0], bq = p[1];
    f[0] = a.x; f[1] = a.y; f[2] = a.z; f[3] = a.w;
    f[4] = bq.x; f[5] = bq.y; f[6] = bq.z; f[7] = bq.w;
  } else {
    bf16x8 v = *(const bf16x8*)((const bf16*)in + base);
#pragma unroll
    for (int i = 0; i < 8; ++i) f[i] = (float)v[i];
  }
  float s = 0.f, sq = 0.f;
#pragma unroll
  for (int i = 0; i < 8; ++i) { s += f[i]; sq += f[i] * f[i]; }
#pragma unroll
  for (int m = 32; m; m >>= 1) { s += __shfl_xor(s, m); sq += __shfl_xor(sq, m); }
  const float mean = s * (1.0f / DIM);
  const float var = fmaxf(sq * (1.0f / DIM) - mean * mean, 0.0f);
  const float rs = rsqrtf(var + EPS);
  bf16x8 gv = *(const bf16x8*)(gg + lane * 8);
  bf16x8 bv = *(const bf16x8*)(bb + lane * 8);
  bf16x8 o;
#pragma unroll
  for (int i = 0; i < 8; ++i) o[i] = (bf16)((f[i] - mean) * rs * (float)gv[i] + (float)bv[i]);
  *(bf16x8*)((bf16*)out + base) = o;
}

// ---------------- GEMM: C = A(MxK) @ Bw(N x K, row-stride bstride)^T ----------------
// 256x128 tile, 8 waves (4M x 2N, per-wave 64x64), 3-buffer depth-2
// COUNTED-vmcnt pipeline (T4) + T2 LDS SWIZZLE on the K-chunk slot:
//   LDS[row][slot] holds global k-chunk (slot ^ ((row>>1)&3)).
//   - Staging keeps the LINEAR gload_lds dest (rule #21) and permutes the
//     GLOBAL source column: src chunk = (c&3) ^ ((c>>3)&3) -- per-thread
//     constant, stays within the same 64B segment (coalescing intact).
//   - Fragment reads use slot = quad ^ ((l15>>1)&3) -- also per-thread
//     constant (wM and i*16 contribute 0 mod 4 after >>1).
//   Fixes the 8-way bank aliasing of row-indexed-by-lane ds_read_b128
//   (row stride 64B => only 2 bank bases); now 2 lanes/bank-slot = free.
// Schedule: stage tile t+2 while computing tile t; per-iteration tail =
// vmcnt(3) + raw s_barrier; never vmcnt(0) in steady state. Stage = 3
// uniform loads/thread. Buffer = 24 KiB; x3 = 72 KiB dynamic LDS ->
// 2 blocks/CU x 8 waves = 16 waves/CU.
// Ledger: b[(t+2)%3] last read at iter t-1, fenced by that iter's tail
// barrier; per-wave vmcnt(3) precedes the barrier so all waves' tile-t+1
// loads are in LDS before any wave reads them. Tail iter t=nt-2 uses
// vmcnt(0); iter nt-1 has no tail sync.
// Epilogues BARRIER-FREE: final iter reads b[(nt-1)%3]; buffers q0=nt%3 and
// q1=(nt+1)%3 are quiescent. b16 restage: 8 waves x 1152 el = 18 KiB <= q0.
// f32 restage: waves 0-5 in q0 (6x4 KiB), waves 6-7 in q1.
// MODE 0: QKV -> q,k,v head-major [bh][n][64]; q/k fused l2norm*scale+rope
// MODE 1: + X(raw x, probe-switched) + bias -> O0 bf16 (stride DIM)
// MODE 2: fast exact gelu -> O0 bf16 (stride ostride)
// MODE 3: + Xb(bf16, stride DIM) -> Of fp32 (stride DIM)
// MODE 4: + Of(read-back fp32)   -> Of fp32 (stride DIM)
template <int MODE>
__global__ __launch_bounds__(512) void gemm_bt(const bf16* __restrict__ A,
                                               const bf16* __restrict__ Bw,
                                               bf16* __restrict__ O0, bf16* __restrict__ O1,
                                               bf16* __restrict__ O2,
                                               float* __restrict__ Of,
                                               const void* __restrict__ Xraw,
                                               const bf16* __restrict__ Xb,
                                               const bf16* __restrict__ bias,
                                               const unsigned short* __restrict__ probe,
                                               int K, int bstride, int ostride, int gx) {
  extern __shared__ __align__(16) bf16 smem[];        // 3 * 12288 elems = 72 KiB
  const int tid = threadIdx.x;
  const int wid = tid >> 6, lane = tid & 63;
  const int l15 = lane & 15, quad = lane >> 4;
  // XCD-aware swizzle (8 m-strips per XCD group, n fastest within)
  const int id = blockIdx.x;
  const int per = gx * 8;
  const int tM = ((id / per) * 8 + (id & 7)) * 256;
  const int tN = ((id % per) >> 3) * 128;
  const int wM = (wid >> 1) * 64, wN = (wid & 1) * 64;
  // T2 read-side swizzled k-slot (per-thread constant; elements)
  const int kq = (quad ^ ((l15 >> 1) & 3)) * 8;
  f32x4 acc[4][4];
  const f32x4 z = {0.f, 0.f, 0.f, 0.f};
#pragma unroll
  for (int i = 0; i < 4; ++i)
#pragma unroll
    for (int j = 0; j < 4; ++j) acc[i][j] = z;

  // T2 stage-side inverse-swizzled global columns (per-thread constants)
  const int cA0 = tid,       rA0 = cA0 >> 2, sA0 = (((cA0 & 3) ^ ((cA0 >> 3) & 3)) * 8);
  const int cA1 = tid + 512, rA1 = cA1 >> 2, sA1 = (((cA1 & 3) ^ ((cA1 >> 3) & 3)) * 8);
  const int cB0 = tid,       rB0 = cB0 >> 2, sB0 = sA0;

  auto stage = [&](int t, int p) {                    // 3 gload_lds per thread
    const int k0 = t * 32;
    bf16* dA = smem + p * 12288;
    bf16* dB = dA + 8192;
    gload_lds16(A  + (size_t)(tM + rA0) * K       + k0 + sA0, &dA[cA0 * 8]);
    gload_lds16(A  + (size_t)(tM + rA1) * K       + k0 + sA1, &dA[cA1 * 8]);
    gload_lds16(Bw + (size_t)(tN + rB0) * bstride + k0 + sB0, &dB[cB0 * 8]);
  };

  const int nt = K >> 5;                              // >= 16 in all uses
  stage(0, 0);
  stage(1, 1);
  __builtin_amdgcn_sched_barrier(0);
  asm volatile("s_waitcnt vmcnt(3)" ::: "memory");    // tile0 landed (tile1 in flight)
  __builtin_amdgcn_s_barrier();
  __builtin_amdgcn_sched_barrier(0);

  int cur = 0;
  for (int t = 0; t < nt; ++t) {
    if (t + 2 < nt) {
      int nx = cur + 2; if (nx >= 3) nx -= 3;
      stage(t + 2, nx);                               // overwrites buffer read at t-1
    }
    const bf16* As = smem + cur * 12288;
    const bf16* Bs = As + 8192;
    bf16x8 aF[4], bF[4];
#pragma unroll
    for (int i = 0; i < 4; ++i) aF[i] = *(const bf16x8*)&As[(wM + i * 16 + l15) * 32 + kq];
#pragma unroll
    for (int j = 0; j < 4; ++j) bF[j] = *(const bf16x8*)&Bs[(wN + j * 16 + l15) * 32 + kq];
#pragma unroll
    for (int i = 0; i < 4; ++i)
#pragma unroll
      for (int j = 0; j < 4; ++j) acc[i][j] = mfma16(aF[i], bF[j], acc[i][j]);
    if (t < nt - 1) {
      __builtin_amdgcn_sched_barrier(0);
      if (t + 2 < nt) asm volatile("s_waitcnt vmcnt(3)" ::: "memory");  // t+1 landed
      else            asm volatile("s_waitcnt vmcnt(0)" ::: "memory");  // drain tail
      __builtin_amdgcn_s_barrier();
      __builtin_amdgcn_sched_barrier(0);
    }
    ++cur; if (cur == 3) cur = 0;
  }
  // quiescent epilogue buffers (see header comment)
  const int q0 = nt % 3;
  int q1 = q0 + 1; if (q1 == 3) q1 = 0;
  bf16* eb = smem + q0 * 12288;

  if constexpr (MODE == 0) {
    // wave's 64-col span is exactly one (q/k/v, head) plane; fused rope for q/k
    bf16* ob = eb + wid * 1152;                       // per-wave 16 x 72 tile
    const int colbase = tN + wN;
    const int which = colbase >> 9;
    const int head = (colbase >> 6) & 7;
    bf16* dst = which == 0 ? O0 : (which == 1 ? O1 : O2);
    const int ch = lane & 7;
    float scv[8], invf[8];
    if (which < 2) {
      const bf16* sc = which ? bias : Xb;             // ksc : qsc
      bf16x8 s8 = *(const bf16x8*)(sc + ch * 8);
#pragma unroll
      for (int u = 0; u < 8; ++u) {
        scv[u] = (float)s8[u] * (which == 0 ? 8.0f : 1.0f);   // fold QK_SCALE into q
        invf[u] = exp2f(-(float)((ch & 3) * 8 + u) * (13.287712379549449f / 32.0f));
      }
    }
#pragma unroll
    for (int i = 0; i < 4; ++i) {
#pragma unroll
      for (int j = 0; j < 4; ++j)
#pragma unroll
        for (int r = 0; r < 4; ++r)
          ob[(quad * 4 + r) * 72 + j * 16 + l15] = (bf16)acc[i][j][r];
#pragma unroll
      for (int t = 0; t < 2; ++t) {
        const int rr = t * 8 + (lane >> 3);
        const int rowg = tM + wM + i * 16 + rr;
        bf16x8 ov = *(const bf16x8*)&ob[rr * 72 + ch * 8];
        float f[8];
#pragma unroll
        for (int u = 0; u < 8; ++u) f[u] = (float)ov[u];
        if (which < 2) {
          float ss = 0.f;
#pragma unroll
          for (int u = 0; u < 8; ++u) ss += f[u] * f[u];
          ss += __shfl_xor(ss, 1); ss += __shfl_xor(ss, 2); ss += __shfl_xor(ss, 4);
          const float rs = 1.0f / fmaxf(sqrtf(ss), 1e-12f);
#pragma unroll
          for (int u = 0; u < 8; ++u) f[u] *= rs * scv[u];
          float pf[8];
#pragma unroll
          for (int u = 0; u < 8; ++u) pf[u] = __shfl_xor(f[u], 4);
          const float pos = (float)(rowg & (SEQ - 1));
#pragma unroll
          for (int u = 0; u < 8; ++u) {
            float sn, cs;
            __sincosf(pos * invf[u], &sn, &cs);
            const float rot = (ch < 4) ? -pf[u] : pf[u];
            f[u] = f[u] * cs + rot * sn;
          }
        }
        bf16x8 o8;
#pragma unroll
        for (int u = 0; u < 8; ++u) o8[u] = (bf16)f[u];
        const int bb = rowg >> 12, n = rowg & (SEQ - 1);
        *(bf16x8*)(dst + ((size_t)(bb * HEADS + head) * SEQ + n) * DH + ch * 8) = o8;
      }
    }
    return;
  }

  if constexpr (MODE == 1 || MODE == 2) {
    // coalesced epilogue via per-wave LDS restage (barrier-free; region in q0)
    bf16* ob = eb + wid * 1152;                       // 16 x 72
    const int ch = lane & 7;
    bf16x8 bias8;
    bool xf32 = false;
    if constexpr (MODE == 1) {
      bias8 = *(const bf16x8*)(bias + tN + wN + ch * 8);
      xf32 = (probe[0] == 0);
    }
#pragma unroll
    for (int i = 0; i < 4; ++i) {
#pragma unroll
      for (int j = 0; j < 4; ++j)
#pragma unroll
        for (int r = 0; r < 4; ++r)
          ob[(quad * 4 + r) * 72 + j * 16 + l15] = (bf16)acc[i][j][r];
#pragma unroll
      for (int t = 0; t < 2; ++t) {
        const int rr = t * 8 + (lane >> 3);
        const int rowg = tM + wM + i * 16 + rr;
        bf16x8 ov = *(const bf16x8*)&ob[rr * 72 + ch * 8];
        bf16x8 o8;
        if constexpr (MODE == 1) {
          const size_t idx = (size_t)rowg * DIM + tN + wN + ch * 8;
          float xr[8];
          if (xf32) {
            const float4* xp = (const float4*)((const float*)Xraw + idx);
            float4 a = xp[0], bq = xp[1];
            xr[0] = a.x; xr[1] = a.y; xr[2] = a.z; xr[3] = a.w;
            xr[4] = bq.x; xr[5] = bq.y; xr[6] = bq.z; xr[7] = bq.w;
          } else {
            bf16x8 xv = *(const bf16x8*)((const bf16*)Xraw + idx);
#pragma unroll
            for (int u = 0; u < 8; ++u) xr[u] = (float)xv[u];
          }
#pragma unroll
          for (int u = 0; u < 8; ++u) o8[u] = (bf16)((float)ov[u] + xr[u] + (float)bias8[u]);
          *(bf16x8*)(O0 + idx) = o8;
        } else {
#pragma unroll
          for (int u = 0; u < 8; ++u) o8[u] = (bf16)fast_gelu((float)ov[u]);
          *(bf16x8*)(O0 + (size_t)rowg * ostride + tN + wN + ch * 8) = o8;
        }
      }
    }
    return;
  }

  if constexpr (MODE == 3 || MODE == 4) {
    // fp32 LDS restage -> float4 stores (barrier-free; waves 0-5 in q0,
    // waves 6-7 in q1; per-wave 16 x 64 floats = 4 KiB)
    float* obf = (wid < 6)
        ? (float*)(smem + q0 * 12288) + wid * 1024
        : (float*)(smem + q1 * 12288) + (wid - 6) * 1024;
    const int ch = lane & 7;
#pragma unroll
    for (int i = 0; i < 4; ++i) {
#pragma unroll
      for (int j = 0; j < 4; ++j)
#pragma unroll
        for (int r = 0; r < 4; ++r)
          obf[(quad * 4 + r) * 64 + j * 16 + l15] = acc[i][j][r];
#pragma unroll
      for (int t = 0; t < 2; ++t) {
        const int rr = t * 8 + (lane >> 3);
        const int rowg = tM + wM + i * 16 + rr;
        const size_t idx = (size_t)rowg * DIM + tN + wN + ch * 8;
        const float4* rp = (const float4*)&obf[rr * 64 + ch * 8];
        float4 a = rp[0], b = rp[1];
        float f[8] = {a.x, a.y, a.z, a.w, b.x, b.y, b.z, b.w};
        if constexpr (MODE == 3) {
          bf16x8 xv = *(const bf16x8*)(Xb + idx);
#pragma unroll
          for (int u = 0; u < 8; ++u) f[u] += (float)xv[u];
        } else {
          const float4* op = (const float4*)(Of + idx);
          float4 oa = op[0], ob4 = op[1];
          f[0] += oa.x; f[1] += oa.y; f[2] += oa.z; f[3] += oa.w;
          f[4] += ob4.x; f[5] += ob4.y; f[6] += ob4.z; f[7] += ob4.w;
        }
        float4 o0 = {f[0], f[1], f[2], f[3]}, o1 = {f[4], f[5], f[6], f[7]};
        ((float4*)(Of + idx))[0] = o0;
        ((float4*)(Of + idx))[1] = o1;
      }
    }
    return;
  }
}

// ---------------- windowed attention: one block per (b,h,window) ----------------
__global__ __launch_bounds__(256, 3) void attn_kernel(const bf16* __restrict__ q,
                                                      const bf16* __restrict__ k,
                                                      const bf16* __restrict__ v,
                                                      bf16* __restrict__ ao) {
  __shared__ __align__(16) bf16 kv[256 * 72];       // K [tok][72]; later V^T [d][264]
  __shared__ __align__(16) bf16 pbuf[4][16 * 136];  // per-wave half-P / O tile
  const int w = blockIdx.x, h = blockIdx.y, b = blockIdx.z;
  const int tid = threadIdx.x;
  const int wv = tid >> 6, lane = tid & 63;
  const int l15 = lane & 15, quad = lane >> 4;
  const size_t bh = (size_t)b * HEADS + h;
  const bf16* qb = q + bh * SEQ * DH;
  const bf16* kb = k + bh * SEQ * DH;
  const bf16* vb = v + bh * SEQ * DH;
  const int t0 = (w - 1) * WIN;                     // tile token range [t0, t0+256)

#pragma unroll
  for (int it = 0; it < 8; ++it) {
    const int c = it * 256 + tid;
    const int tok = c >> 3, ch = c & 7;
    int gt = t0 + tok; gt = gt < 0 ? 0 : gt;
    *(bf16x8*)&kv[tok * 72 + ch * 8] = *(const bf16x8*)(kb + (size_t)gt * DH + ch * 8);
  }
  bf16x8 aQ[2][2];
#pragma unroll
  for (int qt = 0; qt < 2; ++qt) {
    const int qtok = w * WIN + wv * 32 + qt * 16 + l15;
#pragma unroll
    for (int ks = 0; ks < 2; ++ks)
      aQ[qt][ks] = *(const bf16x8*)(qb + (size_t)qtok * DH + ks * 32 + quad * 8);
  }
  int gtv = t0 + tid; gtv = gtv < 0 ? 0 : gtv;
  bf16x8 vld[8];
#pragma unroll
  for (int dg = 0; dg < 8; ++dg)
    vld[dg] = *(const bf16x8*)(vb + (size_t)gtv * DH + dg * 8);
  __syncthreads();

  bf16x8 aP[2][8];
#pragma unroll
  for (int qt = 0; qt < 2; ++qt) {
    f32x4 sreg[16];
#pragma unroll
    for (int nt = 0; nt < 16; ++nt) {
      f32x4 a = {0.f, 0.f, 0.f, 0.f};
#pragma unroll
      for (int ks = 0; ks < 2; ++ks) {
        bf16x8 bK = *(const bf16x8*)&kv[(nt * 16 + l15) * 72 + ks * 32 + quad * 8];
        a = mfma16(aQ[qt][ks], bK, a);
      }
      sreg[nt] = a;
    }
    const int qlb = wv * 32 + qt * 16 + quad * 4;
    float rinv[4];
#pragma unroll
    for (int r = 0; r < 4; ++r) {
      const int ql = qlb + r;
      float sum = 0.f;
#pragma unroll
      for (int nt = 0; nt < 16; ++nt) {
        const int j = nt * 16 + l15;
        const bool valid = (nt < 8) ? (w > 0) : (ql >= j - WIN);
        const float p = valid ? __expf(sreg[nt][r]) : 0.0f;   // no max-sub: |s|<=8
        sreg[nt][r] = p;
        sum += p;
      }
#pragma unroll
      for (int m = 8; m; m >>= 1) sum += __shfl_xor(sum, m);
      rinv[r] = 1.0f / sum;
    }
#pragma unroll
    for (int half = 0; half < 2; ++half) {
#pragma unroll
      for (int ntw = 0; ntw < 8; ++ntw)
#pragma unroll
        for (int r = 0; r < 4; ++r)
          pbuf[wv][(quad * 4 + r) * 136 + ntw * 16 + l15] =
              (bf16)(sreg[half * 8 + ntw][r] * rinv[r]);
#pragma unroll
      for (int kk = 0; kk < 4; ++kk)
        aP[qt][half * 4 + kk] = *(const bf16x8*)&pbuf[wv][l15 * 136 + kk * 32 + quad * 8];
    }
  }
  __syncthreads();

#pragma unroll
  for (int dg = 0; dg < 8; ++dg)
#pragma unroll
    for (int i = 0; i < 8; ++i)
      kv[(dg * 8 + i) * 264 + tid] = vld[dg][i];
  __syncthreads();

#pragma unroll
  for (int qt = 0; qt < 2; ++qt) {
#pragma unroll
    for (int dt = 0; dt < 4; ++dt) {
      f32x4 o = {0.f, 0.f, 0.f, 0.f};
#pragma unroll
      for (int ks2 = 0; ks2 < 8; ++ks2) {
        bf16x8 bV = *(const bf16x8*)&kv[(dt * 16 + l15) * 264 + ks2 * 32 + quad * 8];
        o = mfma16(aP[qt][ks2], bV, o);
      }
#pragma unroll
      for (int r = 0; r < 4; ++r)
        pbuf[wv][(quad * 4 + r) * 136 + dt * 16 + l15] = (bf16)o[r];
    }
#pragma unroll
    for (int t = 0; t < 2; ++t) {
      const int rr = t * 8 + (lane >> 3), ch = lane & 7;
      bf16x8 ov = *(const bf16x8*)&pbuf[wv][rr * 136 + ch * 8];
      const int tok = w * WIN + wv * 32 + qt * 16 + rr;
      *(bf16x8*)(ao + ((size_t)b * SEQ + tok) * DIM + h * DH + ch * 8) = ov;
    }
  }
}

extern "C" void kernel_launch(void* const* d_in, const int* in_sizes, int n_in,
                              void* d_out, int out_size, void* d_ws, size_t ws_size,
                              hipStream_t stream) {
  (void)in_sizes; (void)n_in; (void)out_size;
  float* out = (float*)d_out;                      // fp32 output per reference dtype
  bf16* cano = (bf16*)d_ws;
  const unsigned short* probe = (const unsigned short*)d_in[2];

  SrcPtrs sp;
  for (int i = 0; i < 12; ++i) sp.p[i] = d_in[i];

  bf16* slot0 = cano + P_EL;             // h -> ao -> hf
  bf16* slot1 = cano + P_EL + R_EL;      // q -> x2
  bf16* slot2 = cano + P_EL + 2 * R_EL;  // k ; later f1
  bf16* slot3 = cano + P_EL + 3 * R_EL;  // v (natural head-major layout)

  const bf16* qsc  = cano + C_SM + 0;
  const bf16* ksc  = cano + C_SM + 64;
  const bf16* bout = cano + C_SM + 128;
  const bf16* l1g  = cano + C_SM + 640;
  const bf16* l1b  = cano + C_SM + 1152;
  const bf16* lfg  = cano + C_SM + 1664;
  const bf16* lfb  = cano + C_SM + 2176;

  constexpr int LDSB = 3 * 12288 * 2;    // 73728 B dynamic LDS for gemm_bt
  static bool attr_done = false;
  if (!attr_done) {
    hipFuncSetAttribute((const void*)gemm_bt<0>, hipFuncAttributeMaxDynamicSharedMemorySize, LDSB);
    hipFuncSetAttribute((const void*)gemm_bt<1>, hipFuncAttributeMaxDynamicSharedMemorySize, LDSB);
    hipFuncSetAttribute((const void*)gemm_bt<2>, hipFuncAttributeMaxDynamicSharedMemorySize, LDSB);
    hipFuncSetAttribute((const void*)gemm_bt<3>, hipFuncAttributeMaxDynamicSharedMemorySize, LDSB);
    hipFuncSetAttribute((const void*)gemm_bt<4>, hipFuncAttributeMaxDynamicSharedMemorySize, LDSB);
    attr_done = true;
  }

  ingest_kernel<<<1538, 256, 0, stream>>>(sp, cano);
  ln_kernel<<<TOK / 4, 256, 0, stream>>>(d_in[0], l1g, l1b, slot0, probe, 1);
  gemm_bt<0><<<16 * 96, 512, LDSB, stream>>>(slot0, cano + C_QKV, slot1, slot2, slot3,
                                             nullptr, nullptr, qsc, ksc, probe,
                                             DIM, DIM, 0, 12);
  attn_kernel<<<dim3(NW, HEADS, BATCH), 256, 0, stream>>>(slot1, slot2, slot3, slot0);
  gemm_bt<1><<<16 * 32, 512, LDSB, stream>>>(slot0, cano + C_WOUT, slot1, nullptr, nullptr,
                                             nullptr, d_in[0], nullptr, bout, probe,
                                             DIM, DIM, 0, 4);
  ln_kernel<<<TOK / 4, 256, 0, stream>>>(slot1, lfg, lfb, slot0, probe, 0);

  const bool big = ws_size >= (size_t)(P_EL + 6 * R_EL) * 2;
  if (big) {
    bf16* f1 = slot2;                    // spans slot2..slot5 (4R)
    gemm_bt<2><<<16 * 128, 512, LDSB, stream>>>(slot0, cano + C_WF1, f1, nullptr, nullptr,
                                                nullptr, nullptr, nullptr, nullptr, probe,
                                                DIM, DIM, 2048, 16);
    gemm_bt<3><<<16 * 32, 512, LDSB, stream>>>(f1, cano + C_WF2, nullptr, nullptr, nullptr,
                                               out, nullptr, slot1, nullptr, probe,
                                               2048, 2048, 0, 4);
  } else {
    bf16* f1h = slot2;                   // TOK x 1024 bf16 = 2R
    for (int half = 0; half < 2; ++half) {
      const bf16* w1h = cano + C_WF1 + (size_t)half * 1024 * DIM;
      const bf16* w2h = cano + C_WF2 + (size_t)half * 1024;
      gemm_bt<2><<<16 * 64, 512, LDSB, stream>>>(slot0, w1h, f1h, nullptr, nullptr,
                                                 nullptr, nullptr, nullptr, nullptr, probe,
                                                 DIM, DIM, 1024, 8);
      if (half == 0)
        gemm_bt<3><<<16 * 32, 512, LDSB, stream>>>(f1h, w2h, nullptr, nullptr, nullptr,
                                                   out, nullptr, slot1, nullptr, probe,
                                                   1024, 2048, 0, 4);
      else
        gemm_bt<4><<<16 * 32, 512, LDSB, stream>>>(f1h, w2h, nullptr, nullptr, nullptr,
                                                   out, nullptr, nullptr, nullptr, probe,
                                                   1024, 2048, 0, 4);
    }
  }
}